// Round 6
// baseline (180.181 us; speedup 1.0000x reference)
//
#include <hip/hip_runtime.h>
#include <cmath>

#pragma clang fp contract(off)

using u32 = unsigned int;
using u64 = unsigned long long;
using u16 = unsigned short;
using u8  = unsigned char;

constexpr int B_ = 256, Q_ = 300, C_ = 81, V_ = 117, K_ = 100;
constexpr int QC_ = Q_ * C_;   // 24300
constexpr int KV_ = K_ * V_;   // 11700

// ---- K1: per-part exact top-128 selection ----
constexpr int PARTS = 8;       // row-parts per batch
constexpr int RPP   = 38;      // rows per part (last part: 34)
constexpr int TOPP  = 128;     // keys kept per part (>=100 needed; 128 for pow2)
constexpr int K1T   = 256;     // K1 threads
constexpr int NB1   = 8192;    // histogram bins = prob float-bits >> 19
constexpr int CAP   = 1024;    // candidate buffer / sort size

constexpr int K2T   = 1024;    // K2 threads

__device__ __forceinline__ u64 shfl_xor_u64(u64 v, int mask) {
    u32 lo = (u32)v, hi = (u32)(v >> 32);
    lo = (u32)__shfl_xor((int)lo, mask, 64);
    hi = (u32)__shfl_xor((int)hi, mask, 64);
    return ((u64)hi << 32) | lo;
}

__device__ __forceinline__ float iou1(const float* a, const float* b) {
    float areaA = (a[2] - a[0] + 1.f) * (a[3] - a[1] + 1.f);
    float areaB = (b[2] - b[0] + 1.f) * (b[3] - b[1] + 1.f);
    float xx1 = fmaxf(a[0], b[0]);
    float yy1 = fmaxf(a[1], b[1]);
    float xx2 = fminf(a[2], b[2]);
    float yy2 = fminf(a[3], b[3]);
    float w = fmaxf(0.f, xx2 - xx1 + 1.f);
    float h = fmaxf(0.f, yy2 - yy1 + 1.f);
    float inter = w * h;
    return inter / (areaA + areaB - inter);
}

// =====================================================================
// K1: grid 2048 (= B*PARTS), 256 thr. softmax + per-part exact top-128.
// Keys (prob_bits<<32)|~flat_idx — identical tie semantics to lax.top_k.
// =====================================================================
__global__ __launch_bounds__(K1T) void k1_select(
    const float* __restrict__ obj_logits,   // B,Q,C
    u64* __restrict__ wsc)                  // B x (PARTS*TOPP) keys
{
    const int blk = blockIdx.x;
    const int b = blk >> 3, p = blk & 7;
    const int row0 = p * RPP;
    const int nrows = min(RPP, Q_ - row0);
    const float* lg = obj_logits + (size_t)b * QC_ + (size_t)row0 * C_;
    const int tid = threadIdx.x;

    __shared__ __align__(16) u8 sm[32768 + 64];
    u32* hist  = (u32*)sm;            // [8192]
    u64* cand  = (u64*)sm;            // [1024] aliases hist after threshold
    u32* s_cnt = (u32*)(sm + 32768);
    int* sT    = (int*)(sm + 32772);
    u32* swsum = (u32*)(sm + 32776);  // [4]

    for (int i = tid; i < NB1; i += K1T) hist[i] = 0;
    if (tid == 0) *s_cnt = 0;
    __syncthreads();

    // ---- softmax + histogram, probs stashed in registers ----
    const int g = tid >> 5, l = tid & 31;
    const bool have2 = (l < C_ - 64);   // l < 17
    u32 pb0[5], pb1[5], pb2[5];
    #pragma unroll
    for (int it = 0; it < 5; it++) {
        int r = g + (it << 3);
        if (r < nrows) {
            const float* row = lg + r * C_;
            float v0 = row[l], v1 = row[l + 32];
            float v2 = have2 ? row[l + 64] : -INFINITY;
            float m = fmaxf(fmaxf(v0, v1), v2);
            for (int off = 16; off; off >>= 1) m = fmaxf(m, __shfl_xor(m, off, 64));
            float e0 = __expf(v0 - m), e1 = __expf(v1 - m);
            float e2 = have2 ? __expf(v2 - m) : 0.f;
            float s = e0 + e1 + e2;
            for (int off = 16; off; off >>= 1) s += __shfl_xor(s, off, 64);
            float ri = 1.f / s;
            u32 b0 = __float_as_uint(e0 * ri), b1 = __float_as_uint(e1 * ri);
            pb0[it] = b0; pb1[it] = b1;
            atomicAdd(&hist[b0 >> 19], 1u);
            atomicAdd(&hist[b1 >> 19], 1u);
            if (have2) {
                u32 b2 = __float_as_uint(e2 * ri);
                pb2[it] = b2;
                atomicAdd(&hist[b2 >> 19], 1u);
            }
        }
    }
    __syncthreads();

    // ---- threshold bin T: count(bins >= T) >= TOPP, count(bins > T) < TOPP ----
    {
        u32 c = 0;
        int base = tid * (NB1 / K1T);   // 32 bins/thread
        for (int k = 0; k < NB1 / K1T; k++) c += hist[base + k];
        u32 suf = c;
        #pragma unroll
        for (int off = 1; off < 64; off <<= 1) {
            u32 o = (u32)__shfl_down((int)suf, off, 64);
            suf += ((tid & 63) + off < 64) ? o : 0;
        }
        if ((tid & 63) == 0) swsum[tid >> 6] = suf;
        __syncthreads();
        u32 aw = 0;
        for (int w = (tid >> 6) + 1; w < 4; w++) aw += swsum[w];
        u32 above = aw + (suf - c);      // count in bins strictly above my chunk
        if (above < (u32)TOPP && above + c >= (u32)TOPP) {
            u32 acc = above;
            for (int bn = base + NB1 / K1T - 1; bn >= base; bn--) {
                u32 h = hist[bn];
                if (acc + h >= (u32)TOPP) { *sT = bn; break; }
                acc += h;
            }
        }
    }
    __syncthreads();
    const int T = *sT;
    __syncthreads();   // hist dead; cand alias live

    // ---- collect candidates from register stash ----
    #pragma unroll
    for (int it = 0; it < 5; it++) {
        int r = g + (it << 3);
        if (r < nrows) {
            u32 base_i = (u32)((row0 + r) * C_);
            u32 b0 = pb0[it];
            if ((int)(b0 >> 19) >= T) {
                u32 pos = atomicAdd(s_cnt, 1u);
                if (pos < (u32)CAP) cand[pos] = ((u64)b0 << 32) | (u32)(~(base_i + l));
            }
            u32 b1v = pb1[it];
            if ((int)(b1v >> 19) >= T) {
                u32 pos = atomicAdd(s_cnt, 1u);
                if (pos < (u32)CAP) cand[pos] = ((u64)b1v << 32) | (u32)(~(base_i + l + 32));
            }
            if (have2) {
                u32 b2 = pb2[it];
                if ((int)(b2 >> 19) >= T) {
                    u32 pos = atomicAdd(s_cnt, 1u);
                    if (pos < (u32)CAP) cand[pos] = ((u64)b2 << 32) | (u32)(~(base_i + l + 64));
                }
            }
        }
    }
    __syncthreads();
    int ncand = (int)*s_cnt;
    if (ncand > CAP) ncand = CAP;

    u64* outp = wsc + (size_t)b * (PARTS * TOPP) + p * TOPP;

    auto cswap = [](u64& a, u64& bb, bool up) {
        if ((a > bb) == up) { u64 t = a; a = bb; bb = t; }
    };

    if (ncand <= 256) {
        // ---- register bitonic-256 on wave 0, zero barriers ----
        if (tid < 64) {
            u64 v0 = (tid < ncand) ? cand[tid] : 0ull;
            u64 v1 = (64 + tid < ncand) ? cand[64 + tid] : 0ull;
            u64 v2 = (128 + tid < ncand) ? cand[128 + tid] : 0ull;
            u64 v3 = (192 + tid < ncand) ? cand[192 + tid] : 0ull;
            for (int k = 2; k <= 256; k <<= 1) {
                for (int j = k >> 1; j > 0; j >>= 1) {
                    if (j == 128) {
                        cswap(v0, v2, true);
                        cswap(v1, v3, true);
                    } else if (j == 64) {
                        cswap(v0, v1, true);
                        cswap(v2, v3, (k == 256));
                    } else {
                        auto step = [&](u64& v, int ebase) {
                            u64 pv = shfl_xor_u64(v, j);
                            int e = ebase + tid;
                            bool up = ((e & k) == 0);
                            bool lower = ((e & j) == 0);
                            u64 mn = v < pv ? v : pv;
                            u64 mx = v < pv ? pv : v;
                            v = (lower == up) ? mn : mx;
                        };
                        step(v0, 0); step(v1, 64); step(v2, 128); step(v3, 192);
                    }
                }
            }
            // ascending over 256 slots; ncand>=128 so e in [128,256) are real top-128
            outp[tid]      = v2;   // e = 128+tid
            outp[64 + tid] = v3;   // e = 192+tid
        }
    } else {
        // ---- LDS bitonic-1024 fallback (rare) ----
        for (int e = tid; e < CAP; e += K1T)
            if (e >= ncand) cand[e] = 0;
        __syncthreads();
        for (int k = 2; k <= CAP; k <<= 1) {
            for (int j = k >> 1; j > 0; j >>= 1) {
                for (int e = tid; e < CAP; e += K1T) {
                    int partner = e ^ j;
                    if (partner > e) {
                        u64 a = cand[e], bb = cand[partner];
                        bool up = ((e & k) == 0);
                        if ((a > bb) == up) { cand[e] = bb; cand[partner] = a; }
                    }
                }
                __syncthreads();
            }
        }
        if (tid < TOPP) outp[tid] = cand[CAP - 1 - tid];
    }
}

// =====================================================================
// K2: grid 256, 1024 thr. Merge 1024 keys -> exact top-100, then
// boxes, hoi scores, NMS, outputs.
// =====================================================================
// LDS layout (aliased): cand u64[1024]@0 (until sel extracted),
// hs f32[11700]@0 (phase>=6), then small arrays after 46800.
constexpr int OFF_HS   = 0;
constexpr int OFF_BSUB = 46800;             // f32[100][4]
constexpr int OFF_BOBJ = OFF_BSUB + 1600;   // f32[100][4]
constexpr int OFF_SUPR = OFF_BOBJ + 1600;   // u32[100][4]
constexpr int OFF_SELV = OFF_SUPR + 1600;   // f32[100]
constexpr int OFF_SELI = OFF_SELV + 400;    // u32[100]
constexpr int OFF_MAXB = OFF_SELI + 400;    // u32[100]
constexpr int OFF_ORD  = OFF_MAXB + 400;    // u8[100] pad 104
constexpr int OFF_MISC = OFF_ORD + 104;     // skeep[4], keep_bits[4]
constexpr int SMEM2    = OFF_MISC + 32;     // 52,936
static_assert(SMEM2 <= 65536, "LDS overflow");

__global__ __launch_bounds__(K2T) void k2_finish(
    const u64*  __restrict__ wsc,           // B x 1024 keys
    const float* __restrict__ verb_logits,  // B,Q,V
    const float* __restrict__ sub_boxes_in, // B,Q,4
    const float* __restrict__ obj_boxes_in, // B,Q,4
    const float* __restrict__ cm,           // V,C
    const int*   __restrict__ tsizes,       // B,2 (h,w)
    float* __restrict__ out)
{
    const int b = blockIdx.x;
    const int tid = threadIdx.x;

    __shared__ __align__(16) u8 smem[SMEM2];
    u64*   cand    = (u64*)(smem + OFF_HS);
    float* hs      = (float*)(smem + OFF_HS);
    float (*bsub)[4]   = (float(*)[4])(smem + OFF_BSUB);
    float (*bobj)[4]   = (float(*)[4])(smem + OFF_BOBJ);
    u32   (*suprow)[4] = (u32(*)[4])(smem + OFF_SUPR);
    float* sel_val = (float*)(smem + OFF_SELV);
    u32*   sel_idx = (u32*)(smem + OFF_SELI);
    u32*   maxbits = (u32*)(smem + OFF_MAXB);
    u8*    order8  = (u8*)(smem + OFF_ORD);
    u32*   skeep     = (u32*)(smem + OFF_MISC);
    u32*   keep_bits = (u32*)(smem + OFF_MISC + 16);

    // ---- load 1024 keys, bitonic sort ascending ----
    cand[tid] = wsc[(size_t)b * (PARTS * TOPP) + tid];
    __syncthreads();
    for (int k = 2; k <= CAP; k <<= 1) {
        for (int j = k >> 1; j > 0; j >>= 1) {
            int e = tid, partner = e ^ j;
            if (partner > e) {
                u64 a = cand[e], bb = cand[partner];
                bool up = ((e & k) == 0);
                if ((a > bb) == up) { cand[e] = bb; cand[partner] = a; }
            }
            __syncthreads();
        }
    }
    if (tid < K_) {
        u64 m = cand[CAP - 1 - tid];
        u32 idx = ~(u32)m;
        if (idx >= (u32)QC_) idx = 0;   // defensive
        sel_val[tid] = __uint_as_float((u32)(m >> 32));
        sel_idx[tid] = idx;
    }
    __syncthreads();   // sel_* visible; cand dead (hs may now alias)

    // ---- gather + scale boxes; init NMS state ----
    if (tid < K_) {
        int idx = (int)sel_idx[tid];
        int q = idx / C_;
        float iw = (float)tsizes[b * 2 + 1];
        float ih = (float)tsizes[b * 2 + 0];
        float4 sb = ((const float4*)sub_boxes_in)[(size_t)b * Q_ + q];
        float4 ob = ((const float4*)obj_boxes_in)[(size_t)b * Q_ + q];
        bsub[tid][0] = (sb.x - 0.5f * sb.z) * iw; bsub[tid][1] = (sb.y - 0.5f * sb.w) * ih;
        bsub[tid][2] = (sb.x + 0.5f * sb.z) * iw; bsub[tid][3] = (sb.y + 0.5f * sb.w) * ih;
        bobj[tid][0] = (ob.x - 0.5f * ob.z) * iw; bobj[tid][1] = (ob.y - 0.5f * ob.w) * ih;
        bobj[tid][2] = (ob.x + 0.5f * ob.z) * iw; bobj[tid][3] = (ob.y + 0.5f * ob.w) * ih;
        suprow[tid][0] = 0; suprow[tid][1] = 0; suprow[tid][2] = 0; suprow[tid][3] = 0;
    }
    if (tid >= 128 && tid < 132) keep_bits[tid - 128] = 0;
    __syncthreads();

    // ---- hoi scores into hs ----
    for (int f = tid; f < KV_; f += K2T) {
        int r = f / V_, v = f - r * V_;
        int idx = (int)sel_idx[r];
        int q = idx / C_, lab = idx - q * C_;
        float x = verb_logits[((size_t)b * Q_ + q) * V_ + v];
        float s = 1.f / (1.f + __expf(-x));
        hs[f] = s * sel_val[r] * cm[v * C_ + lab];
    }
    __syncthreads();

    // ---- per-row max, 8 lanes/row ----
    if (tid < 800) {
        int r = tid >> 3, j = tid & 7;
        float m = 0.f;
        for (int k = 0; k < 15; k++) {
            int v = j * 15 + k;
            if (v < V_) m = fmaxf(m, hs[r * V_ + v]);
        }
        for (int off = 4; off; off >>= 1) m = fmaxf(m, __shfl_xor(m, off, 64));
        if (j == 0) maxbits[r] = __float_as_uint(m);
    }
    __syncthreads();

    // ---- stable descending rank ----
    if (tid < 800) {
        int r = tid >> 3, j = tid & 7;
        u64 kr = ((u64)maxbits[r] << 32) | (u32)(~r);
        int rank = 0;
        for (int k = 0; k < 13; k++) {
            int jj = j * 13 + k;
            if (jj < K_) {
                u64 kj = ((u64)maxbits[jj] << 32) | (u32)(~jj);
                rank += (kj > kr) ? 1 : 0;
            }
        }
        for (int off = 4; off; off >>= 1) rank += __shfl_xor(rank, off, 64);
        if (j == 0) order8[rank] = (u8)r;
    }
    __syncthreads();

    // ---- 100x100 suppression bitmatrix in sorted space ----
    for (int e = tid; e < K_ * K_; e += K2T) {
        int i = e / K_, j = e - i * K_;
        if (j > i) {
            int ri = order8[i], rj = order8[j];
            u32 li = sel_idx[ri] % (u32)C_, lj = sel_idx[rj] % (u32)C_;
            if (li == lj) {
                float o = iou1(bsub[ri], bsub[rj]) * iou1(bobj[ri], bobj[rj]);
                if (o > 0.5f)
                    atomicOr(&suprow[i][j >> 5], 1u << (j & 31));
            }
        }
    }
    __syncthreads();

    // ---- greedy scan: single wave, register-resident ----
    if (tid < 64) {
        u32 ra0 = suprow[tid][0], ra1 = suprow[tid][1], ra2 = suprow[tid][2], ra3 = suprow[tid][3];
        u32 rb0 = 0, rb1 = 0, rb2 = 0, rb3 = 0;
        if (tid < K_ - 64) {
            rb0 = suprow[tid + 64][0]; rb1 = suprow[tid + 64][1];
            rb2 = suprow[tid + 64][2]; rb3 = suprow[tid + 64][3];
        }
        u32 acc[4] = {0, 0, 0, 0};
        u32 km[4]  = {0, 0, 0, 0};
        #pragma unroll
        for (int i = 0; i < K_; i++) {
            u32 r0, r1, r2, r3;
            if (i < 64) {
                r0 = (u32)__shfl((int)ra0, i, 64); r1 = (u32)__shfl((int)ra1, i, 64);
                r2 = (u32)__shfl((int)ra2, i, 64); r3 = (u32)__shfl((int)ra3, i, 64);
            } else {
                r0 = (u32)__shfl((int)rb0, i - 64, 64); r1 = (u32)__shfl((int)rb1, i - 64, 64);
                r2 = (u32)__shfl((int)rb2, i - 64, 64); r3 = (u32)__shfl((int)rb3, i - 64, 64);
            }
            bool sup_i = (acc[i >> 5] >> (i & 31)) & 1u;
            if (!sup_i) {
                km[i >> 5] |= 1u << (i & 31);
                acc[0] |= r0; acc[1] |= r1; acc[2] |= r2; acc[3] |= r3;
            }
        }
        if (tid == 0) { skeep[0] = km[0]; skeep[1] = km[1]; skeep[2] = km[2]; skeep[3] = km[3]; }
    }
    __syncthreads();
    if (tid < K_) {
        if ((skeep[tid >> 5] >> (tid & 31)) & 1u) {
            int r = order8[tid];
            atomicOr(&keep_bits[r >> 5], 1u << (r & 31));
        }
    }
    __syncthreads();

    // ---- write outputs (float32, concatenated in return order) ----
    float* o0 = out;                                   // final_scores B,K,V
    float* o1 = out + (size_t)B_ * KV_;                // topk_values  B,K
    float* o2 = o1 + (size_t)B_ * K_;                  // obj_labels   B,K
    float* o3 = o2 + (size_t)B_ * K_;                  // sub_boxes    B,K,4
    float* o4 = o3 + (size_t)B_ * K_ * 4;              // obj_boxes    B,K,4
    float* o5 = o4 + (size_t)B_ * K_ * 4;              // keep         B,K

    for (int f = tid; f < KV_; f += K2T) {
        int r = f / V_;
        bool kp = (keep_bits[r >> 5] >> (r & 31)) & 1u;
        o0[(size_t)b * KV_ + f] = kp ? hs[f] : 0.f;
    }
    if (tid < K_) {
        bool kp = (keep_bits[tid >> 5] >> (tid & 31)) & 1u;
        o1[(size_t)b * K_ + tid] = sel_val[tid];
        o2[(size_t)b * K_ + tid] = (float)(sel_idx[tid] % (u32)C_);
        o5[(size_t)b * K_ + tid] = kp ? 1.f : 0.f;
    }
    if (tid < K_ * 4) {
        int r = tid >> 2, k = tid & 3;
        o3[((size_t)b * K_) * 4 + tid] = bsub[r][k];
        o4[((size_t)b * K_) * 4 + tid] = bobj[r][k];
    }
}

extern "C" void kernel_launch(void* const* d_in, const int* in_sizes, int n_in,
                              void* d_out, int out_size, void* d_ws, size_t ws_size,
                              hipStream_t stream) {
    const float* obj_logits  = (const float*)d_in[0];
    const float* verb_logits = (const float*)d_in[1];
    const float* sub_boxes   = (const float*)d_in[2];
    const float* obj_boxes   = (const float*)d_in[3];
    const float* cm          = (const float*)d_in[4];
    const int*   ts          = (const int*)d_in[5];
    u64* wsc = (u64*)d_ws;    // needs B_*PARTS*TOPP*8 = 2 MiB

    hipLaunchKernelGGL(k1_select, dim3(B_ * PARTS), dim3(K1T), 0, stream,
                       obj_logits, wsc);
    hipLaunchKernelGGL(k2_finish, dim3(B_), dim3(K2T), 0, stream,
                       wsc, verb_logits, sub_boxes, obj_boxes, cm, ts,
                       (float*)d_out);
}

// Round 7
// 160.398 us; speedup vs baseline: 1.1233x; 1.1233x over previous
//
#include <hip/hip_runtime.h>
#include <cmath>

#pragma clang fp contract(off)

#define NT 1024
constexpr int B_ = 256, Q_ = 300, C_ = 81, V_ = 117, K_ = 100;
constexpr int QC_ = Q_ * C_;   // 24300
constexpr int KV_ = K_ * V_;   // 11700
constexpr int NB  = 2048;      // histogram bins = prob float-bits >> 21
constexpr int CAP = 1024;      // LDS candidate buffer (fallback sort size)

using u32 = unsigned int;
using u64 = unsigned long long;
using u16 = unsigned short;
using u8  = unsigned char;

// ---- LDS layout (lifetime-aliased, hand-packed; 65,344 B <= 64 KiB) ----
constexpr int OFF_P16  = 0;                 // u16[24300]=48600 | hs f32[11700]=46800 (phase>=6)
constexpr int OFF_HIST = 48600;             // u32[2048]=8192   | cand u64[1024] (after threshold)
constexpr int OFF_RMAX = OFF_HIST + 8192;   // f32[300]
constexpr int OFF_RINV = OFF_RMAX + 1200;   // f32[300] per-row 1/sum
constexpr int OFF_BSUB = OFF_RINV + 1200;   // f32[100][4] | swsum u32[16] (phase 3)
constexpr int OFF_BOBJ = OFF_BSUB + 1600;   // f32[100][4] | wred u64[16] (fallback 5c)
constexpr int OFF_SUPR = OFF_BOBJ + 1600;   // u32[100][4] | s_prev u64 (fallback 5c)
constexpr int OFF_SELV = OFF_SUPR + 1600;   // f32[100]
constexpr int OFF_SELI = OFF_SELV + 400;    // u32[100] flat topk index
constexpr int OFF_MAXB = OFF_SELI + 400;    // u32[100] row-max bits
constexpr int OFF_ORD  = OFF_MAXB + 400;    // u8[100] (pad 104)
constexpr int OFF_MISC = OFF_ORD + 104;     // skeep[4], keep_bits[4], s_cnt, sT, sW, sAcc
constexpr int SMEM_SZ  = OFF_MISC + 48;     // 65,344
static_assert(SMEM_SZ <= 65536, "LDS overflow");

__device__ __forceinline__ u64 shfl_xor_u64(u64 v, int mask) {
    u32 lo = (u32)v, hi = (u32)(v >> 32);
    lo = (u32)__shfl_xor((int)lo, mask, 64);
    hi = (u32)__shfl_xor((int)hi, mask, 64);
    return ((u64)hi << 32) | lo;
}

__device__ __forceinline__ float iou1(const float* a, const float* b) {
    float areaA = (a[2] - a[0] + 1.f) * (a[3] - a[1] + 1.f);
    float areaB = (b[2] - b[0] + 1.f) * (b[3] - b[1] + 1.f);
    float xx1 = fmaxf(a[0], b[0]);
    float yy1 = fmaxf(a[1], b[1]);
    float xx2 = fminf(a[2], b[2]);
    float yy2 = fminf(a[3], b[3]);
    float w = fmaxf(0.f, xx2 - xx1 + 1.f);
    float h = fmaxf(0.f, yy2 - yy1 + 1.f);
    float inter = w * h;
    return inter / (areaA + areaB - inter);
}

__global__ __launch_bounds__(NT) void hoi_kernel(
    const float* __restrict__ obj_logits,   // B,Q,C
    const float* __restrict__ verb_logits,  // B,Q,V
    const float* __restrict__ sub_boxes_in, // B,Q,4
    const float* __restrict__ obj_boxes_in, // B,Q,4
    const float* __restrict__ cm,           // V,C
    const int*   __restrict__ tsizes,       // B,2 (h,w)
    float* __restrict__ out)
{
    const int b = blockIdx.x;
    const int tid = threadIdx.x;

    __shared__ __align__(16) u8 smem[SMEM_SZ];
    u16*   p16     = (u16*)(smem + OFF_P16);
    float* hs      = (float*)(smem + OFF_P16);
    u32*   hist    = (u32*)(smem + OFF_HIST);
    u64*   cand    = (u64*)(smem + OFF_HIST);
    float* rowmax  = (float*)(smem + OFF_RMAX);
    float* rinv    = (float*)(smem + OFF_RINV);
    float (*bsub)[4]   = (float(*)[4])(smem + OFF_BSUB);
    float (*bobj)[4]   = (float(*)[4])(smem + OFF_BOBJ);
    u32   (*suprow)[4] = (u32(*)[4])(smem + OFF_SUPR);
    float* sel_val = (float*)(smem + OFF_SELV);
    u32*   sel_idx = (u32*)(smem + OFF_SELI);
    u32*   maxbits = (u32*)(smem + OFF_MAXB);
    u8*    order8  = (u8*)(smem + OFF_ORD);
    u32*   skeep     = (u32*)(smem + OFF_MISC);
    u32*   keep_bits = (u32*)(smem + OFF_MISC + 16);
    u32*   s_cnt     = (u32*)(smem + OFF_MISC + 32);
    int*   sT        = (int*)(smem + OFF_MISC + 36);
    int*   sW        = (int*)(smem + OFF_MISC + 40);
    u32*   sAcc      = (u32*)(smem + OFF_MISC + 44);
    u32*   swsum   = (u32*)(smem + OFF_BSUB);   // phase-3 scratch
    u64*   wred    = (u64*)(smem + OFF_BOBJ);   // 5c scratch
    u64*   s_prev  = (u64*)(smem + OFF_SUPR);   // 5c scratch

    const float* lg = obj_logits + (size_t)b * QC_;

    for (int i = tid; i < NB; i += NT) hist[i] = 0;
    if (tid == 0) *s_cnt = 0;
    __syncthreads();

    // ---- Phase 1: ONE THREAD PER ROW softmax (no cross-lane ops, no shfl chains).
    // Three passes over the 81-element row; loads are independent (deep MLP) and
    // L1/L2-hot after pass A. Probs binned + cached as p16. ----
    if (tid < Q_) {
        const float* row = lg + tid * C_;
        float m = -INFINITY;
        for (int c = 0; c < C_; c++) m = fmaxf(m, row[c]);
        float s = 0.f;
        for (int c = 0; c < C_; c++) s += __expf(row[c] - m);
        float ri = 1.f / s;
        rowmax[tid] = m;
        rinv[tid]   = ri;
        u16* prow = p16 + tid * C_;
        for (int c = 0; c < C_; c++) {
            u32 pb = __float_as_uint(__expf(row[c] - m) * ri);
            prow[c] = (u16)(pb >> 16);
            atomicAdd(&hist[pb >> 21], 1u);
        }
    }
    __syncthreads();

    // ---- Phase 3: threshold bin T via two-level shfl suffix-scan ----
    u32 my_c, my_suf;
    {
        int t = tid;
        my_c = hist[2 * t] + hist[2 * t + 1];
        my_suf = my_c;
        #pragma unroll
        for (int off = 1; off < 64; off <<= 1) {
            u32 o = (u32)__shfl_down((int)my_suf, off, 64);
            my_suf += ((tid & 63) + off < 64) ? o : 0;
        }
        if ((tid & 63) == 0) swsum[tid >> 6] = my_suf;
    }
    __syncthreads();
    if (tid < 16) {
        u32 sufW = swsum[tid];
        #pragma unroll
        for (int off = 1; off < 16; off <<= 1) {
            u32 o = (u32)__shfl_down((int)sufW, off, 64);
            sufW += (tid + off < 16) ? o : 0;
        }
        u32 nxt = (u32)__shfl_down((int)sufW, 1, 64);
        if (tid == 15) nxt = 0;
        if (sufW >= (u32)K_ && nxt < (u32)K_) { *sW = tid; *sAcc = nxt; }
    }
    __syncthreads();
    if ((tid >> 6) == *sW) {
        u32 above = *sAcc + (my_suf - my_c);
        if (above < (u32)K_ && above + my_c >= (u32)K_) {
            u32 acc = above + hist[2 * tid + 1];
            *sT = (acc >= (u32)K_) ? (2 * tid + 1) : (2 * tid);
        }
    }
    __syncthreads();
    const int T = *sT;
    __syncthreads();   // hist reads done; cand may alias

    // ---- Phase 4: scan p16 cache; exact keys recomputed only for candidates ----
    for (int i = tid; i < QC_; i += NT) {
        u32 pb = p16[i];
        if ((int)(pb >> 5) >= T) {
            u32 pos = atomicAdd(s_cnt, 1u);
            if (pos < (u32)CAP) {
                int q = i / C_;
                float p = __expf(lg[i] - rowmax[q]) * rinv[q];  // bit-identical to phase 1
                cand[pos] = ((u64)__float_as_uint(p) << 32) | (u32)(~i);
            }
        }
    }
    __syncthreads();
    const int ncand = (int)*s_cnt;

    auto cswap = [](u64& a, u64& bb, bool up) {
        if ((a > bb) == up) { u64 t = a; a = bb; bb = t; }
    };

    if (ncand <= 256) {
        // ---- Phase 5a: register-resident bitonic-256 on wave 0 — zero barriers ----
        if (tid < 64) {
            u64 v0 = (tid < ncand) ? cand[tid] : 0ull;
            u64 v1 = (64 + tid < ncand) ? cand[64 + tid] : 0ull;
            u64 v2 = (128 + tid < ncand) ? cand[128 + tid] : 0ull;
            u64 v3 = (192 + tid < ncand) ? cand[192 + tid] : 0ull;
            for (int k = 2; k <= 256; k <<= 1) {
                for (int j = k >> 1; j > 0; j >>= 1) {
                    if (j == 128) {
                        cswap(v0, v2, true);
                        cswap(v1, v3, true);
                    } else if (j == 64) {
                        cswap(v0, v1, true);
                        cswap(v2, v3, (k == 256));
                    } else {
                        auto step = [&](u64& v, int ebase) {
                            u64 pv = shfl_xor_u64(v, j);
                            int e = ebase + tid;
                            bool up = ((e & k) == 0);
                            bool lower = ((e & j) == 0);
                            u64 mn = v < pv ? v : pv;
                            u64 mx = v < pv ? pv : v;
                            v = (lower == up) ? mn : mx;
                        };
                        step(v0, 0); step(v1, 64); step(v2, 128); step(v3, 192);
                    }
                }
            }
            int e2 = 128 + tid;
            if (e2 >= 156) {
                int t = 255 - e2;
                sel_val[t] = __uint_as_float((u32)(v2 >> 32));
                sel_idx[t] = ~(u32)v2;
            }
            int t3 = 255 - (192 + tid);
            sel_val[t3] = __uint_as_float((u32)(v3 >> 32));
            sel_idx[t3] = ~(u32)v3;
        }
    } else if (ncand <= CAP) {
        // ---- Phase 5b: LDS bitonic-1024 fallback ----
        for (int e = tid; e < CAP; e += NT)
            if (e >= ncand) cand[e] = 0;
        __syncthreads();
        for (int k = 2; k <= CAP; k <<= 1) {
            for (int j = k >> 1; j > 0; j >>= 1) {
                int e = tid, partner = e ^ j;
                if (partner > e) {
                    u64 a = cand[e], bb = cand[partner];
                    bool up = ((e & k) == 0);
                    if ((a > bb) == up) { cand[e] = bb; cand[partner] = a; }
                }
                __syncthreads();
            }
        }
        if (tid < K_) {
            u64 m = cand[CAP - 1 - tid];
            sel_val[tid] = __uint_as_float((u32)(m >> 32));
            sel_idx[tid] = ~(u32)m;
        }
    } else {
        // ---- Phase 5c (near-dead): 100-round argmax with strict-less chaining ----
        if (tid == 0) *s_prev = ~0ull;
        __syncthreads();
        for (int r = 0; r < K_; r++) {
            u64 prev = *s_prev;
            u64 local = 0;
            for (int i = tid; i < QC_; i += NT) {
                int q = i / C_;
                float p = __expf(lg[i] - rowmax[q]) * rinv[q];
                u64 key = ((u64)__float_as_uint(p) << 32) | (u32)(~i);
                if (key < prev && key > local) local = key;
            }
            for (int off = 32; off > 0; off >>= 1) {
                u64 o = shfl_xor_u64(local, off);
                if (o > local) local = o;
            }
            if ((tid & 63) == 0) wred[tid >> 6] = local;
            __syncthreads();
            if (tid == 0) {
                u64 m = wred[0];
                for (int wv = 1; wv < 16; wv++) if (wred[wv] > m) m = wred[wv];
                *s_prev = m;
                u32 idx = ~(u32)m;
                if (idx >= (u32)QC_) idx = 0;
                sel_val[r] = __uint_as_float((u32)(m >> 32));
                sel_idx[r] = idx;
            }
            __syncthreads();
        }
    }
    __syncthreads();   // sel_* visible; p16/hist/cand/rowstats dead

    // ---- Phase 5.5: gather + scale boxes; init NMS state ----
    if (tid < K_) {
        int idx = (int)sel_idx[tid];
        int q = idx / C_;
        float iw = (float)tsizes[b * 2 + 1];
        float ih = (float)tsizes[b * 2 + 0];
        float4 sb = ((const float4*)sub_boxes_in)[(size_t)b * Q_ + q];
        float4 ob = ((const float4*)obj_boxes_in)[(size_t)b * Q_ + q];
        bsub[tid][0] = (sb.x - 0.5f * sb.z) * iw; bsub[tid][1] = (sb.y - 0.5f * sb.w) * ih;
        bsub[tid][2] = (sb.x + 0.5f * sb.z) * iw; bsub[tid][3] = (sb.y + 0.5f * sb.w) * ih;
        bobj[tid][0] = (ob.x - 0.5f * ob.z) * iw; bobj[tid][1] = (ob.y - 0.5f * ob.w) * ih;
        bobj[tid][2] = (ob.x + 0.5f * ob.z) * iw; bobj[tid][3] = (ob.y + 0.5f * ob.w) * ih;
        suprow[tid][0] = 0; suprow[tid][1] = 0; suprow[tid][2] = 0; suprow[tid][3] = 0;
    }
    if (tid >= 128 && tid < 132) keep_bits[tid - 128] = 0;
    __syncthreads();

    // ---- Phase 6: hoi scores into hs (plain stores; no same-address atomics) ----
    for (int f = tid; f < KV_; f += NT) {
        int r = f / V_, v = f - r * V_;
        int idx = (int)sel_idx[r];
        int q = idx / C_, lab = idx - q * C_;
        float x = verb_logits[((size_t)b * Q_ + q) * V_ + v];
        float s = 1.f / (1.f + __expf(-x));
        hs[f] = s * sel_val[r] * cm[v * C_ + lab];
    }
    __syncthreads();

    // ---- Phase 6.5: per-row max, 8 lanes/row, shfl-reduce ----
    if (tid < 800) {
        int r = tid >> 3, j = tid & 7;
        float m = 0.f;   // hvals >= 0
        for (int k = 0; k < 15; k++) {
            int v = j * 15 + k;
            if (v < V_) m = fmaxf(m, hs[r * V_ + v]);
        }
        for (int off = 4; off; off >>= 1) m = fmaxf(m, __shfl_xor(m, off, 64));
        if (j == 0) maxbits[r] = __float_as_uint(m);
    }
    __syncthreads();

    // ---- Phase 7: stable descending rank, 8 lanes/row, shfl-sum ----
    if (tid < 800) {
        int r = tid >> 3, j = tid & 7;
        u64 kr = ((u64)maxbits[r] << 32) | (u32)(~r);
        int rank = 0;
        for (int k = 0; k < 13; k++) {
            int jj = j * 13 + k;
            if (jj < K_) {
                u64 kj = ((u64)maxbits[jj] << 32) | (u32)(~jj);
                rank += (kj > kr) ? 1 : 0;
            }
        }
        for (int off = 4; off; off >>= 1) rank += __shfl_xor(rank, off, 64);
        if (j == 0) order8[rank] = (u8)r;
    }
    __syncthreads();

    // ---- Phase 8a: 100x100 suppression bitmatrix in sorted space ----
    for (int e = tid; e < K_ * K_; e += NT) {
        int i = e / K_, j = e - i * K_;
        if (j > i) {
            int ri = order8[i], rj = order8[j];
            u32 li = sel_idx[ri] % (u32)C_, lj = sel_idx[rj] % (u32)C_;
            if (li == lj) {
                float o = iou1(bsub[ri], bsub[rj]) * iou1(bobj[ri], bobj[rj]);
                if (o > 0.5f)
                    atomicOr(&suprow[i][j >> 5], 1u << (j & 31));
            }
        }
    }
    __syncthreads();

    // ---- Phase 8b: greedy scan — single wave, register-resident, zero barriers ----
    if (tid < 64) {
        u32 ra0 = suprow[tid][0], ra1 = suprow[tid][1], ra2 = suprow[tid][2], ra3 = suprow[tid][3];
        u32 rb0 = 0, rb1 = 0, rb2 = 0, rb3 = 0;
        if (tid < K_ - 64) {
            rb0 = suprow[tid + 64][0]; rb1 = suprow[tid + 64][1];
            rb2 = suprow[tid + 64][2]; rb3 = suprow[tid + 64][3];
        }
        u32 acc[4] = {0, 0, 0, 0};
        u32 km[4]  = {0, 0, 0, 0};
        #pragma unroll
        for (int i = 0; i < K_; i++) {
            u32 r0, r1, r2, r3;
            if (i < 64) {
                r0 = (u32)__shfl((int)ra0, i, 64); r1 = (u32)__shfl((int)ra1, i, 64);
                r2 = (u32)__shfl((int)ra2, i, 64); r3 = (u32)__shfl((int)ra3, i, 64);
            } else {
                r0 = (u32)__shfl((int)rb0, i - 64, 64); r1 = (u32)__shfl((int)rb1, i - 64, 64);
                r2 = (u32)__shfl((int)rb2, i - 64, 64); r3 = (u32)__shfl((int)rb3, i - 64, 64);
            }
            bool sup_i = (acc[i >> 5] >> (i & 31)) & 1u;
            if (!sup_i) {
                km[i >> 5] |= 1u << (i & 31);
                acc[0] |= r0; acc[1] |= r1; acc[2] |= r2; acc[3] |= r3;
            }
        }
        if (tid == 0) { skeep[0] = km[0]; skeep[1] = km[1]; skeep[2] = km[2]; skeep[3] = km[3]; }
    }
    __syncthreads();
    if (tid < K_) {
        if ((skeep[tid >> 5] >> (tid & 31)) & 1u) {
            int r = order8[tid];
            atomicOr(&keep_bits[r >> 5], 1u << (r & 31));
        }
    }
    __syncthreads();

    // ---- Phase 9: write outputs (float32, concatenated in return order) ----
    float* o0 = out;                                   // final_scores B,K,V
    float* o1 = out + (size_t)B_ * KV_;                // topk_values  B,K
    float* o2 = o1 + (size_t)B_ * K_;                  // obj_labels   B,K
    float* o3 = o2 + (size_t)B_ * K_;                  // sub_boxes    B,K,4
    float* o4 = o3 + (size_t)B_ * K_ * 4;              // obj_boxes    B,K,4
    float* o5 = o4 + (size_t)B_ * K_ * 4;              // keep         B,K

    for (int f = tid; f < KV_; f += NT) {
        int r = f / V_;
        bool kp = (keep_bits[r >> 5] >> (r & 31)) & 1u;
        o0[(size_t)b * KV_ + f] = kp ? hs[f] : 0.f;
    }
    if (tid < K_) {
        bool kp = (keep_bits[tid >> 5] >> (tid & 31)) & 1u;
        o1[(size_t)b * K_ + tid] = sel_val[tid];
        o2[(size_t)b * K_ + tid] = (float)(sel_idx[tid] % (u32)C_);
        o5[(size_t)b * K_ + tid] = kp ? 1.f : 0.f;
    }
    if (tid < K_ * 4) {
        int r = tid >> 2, k = tid & 3;
        o3[((size_t)b * K_) * 4 + tid] = bsub[r][k];
        o4[((size_t)b * K_) * 4 + tid] = bobj[r][k];
    }
}

extern "C" void kernel_launch(void* const* d_in, const int* in_sizes, int n_in,
                              void* d_out, int out_size, void* d_ws, size_t ws_size,
                              hipStream_t stream) {
    const float* obj_logits  = (const float*)d_in[0];
    const float* verb_logits = (const float*)d_in[1];
    const float* sub_boxes   = (const float*)d_in[2];
    const float* obj_boxes   = (const float*)d_in[3];
    const float* cm          = (const float*)d_in[4];
    const int*   ts          = (const int*)d_in[5];
    hipLaunchKernelGGL(hoi_kernel, dim3(B_), dim3(NT), 0, stream,
                       obj_logits, verb_logits, sub_boxes, obj_boxes, cm, ts,
                       (float*)d_out);
}

// Round 8
// 146.821 us; speedup vs baseline: 1.2272x; 1.0925x over previous
//
#include <hip/hip_runtime.h>
#include <cmath>

#pragma clang fp contract(off)

#define NT 1024
constexpr int B_ = 256, Q_ = 300, C_ = 81, V_ = 117, K_ = 100;
constexpr int QC_ = Q_ * C_;   // 24300
constexpr int KV_ = K_ * V_;   // 11700
constexpr int NB  = 2048;      // histogram bins = prob float-bits >> 21
constexpr int CAP = 1024;      // candidate buffer (fallback sort size)
constexpr int HROWS = 150;     // rows per half (K1)
constexpr int HQC   = HROWS * C_;  // 12150
constexpr int TOPH  = 128;     // keys kept per half

using u32 = unsigned int;
using u64 = unsigned long long;
using u16 = unsigned short;
using u8  = unsigned char;

__device__ __forceinline__ u64 shfl_xor_u64(u64 v, int mask) {
    u32 lo = (u32)v, hi = (u32)(v >> 32);
    lo = (u32)__shfl_xor((int)lo, mask, 64);
    hi = (u32)__shfl_xor((int)hi, mask, 64);
    return ((u64)hi << 32) | lo;
}

__device__ __forceinline__ float iou1(const float* a, const float* b) {
    float areaA = (a[2] - a[0] + 1.f) * (a[3] - a[1] + 1.f);
    float areaB = (b[2] - b[0] + 1.f) * (b[3] - b[1] + 1.f);
    float xx1 = fmaxf(a[0], b[0]);
    float yy1 = fmaxf(a[1], b[1]);
    float xx2 = fminf(a[2], b[2]);
    float yy2 = fminf(a[3], b[3]);
    float w = fmaxf(0.f, xx2 - xx1 + 1.f);
    float h = fmaxf(0.f, yy2 - yy1 + 1.f);
    float inter = w * h;
    return inter / (areaA + areaB - inter);
}

// =====================================================================
// K1: grid 512 (batch, half), NT 1024, 2 blocks/CU -> 32 waves/CU.
// R5 front-end on 150 rows; writes ascending top-128 keys per half.
// =====================================================================
constexpr int OFF1_P16  = 0;                   // u16[12150] = 24300 (pad 24304)
constexpr int OFF1_HIST = 24304;               // u32[2048] = 8192 | cand u64[1024] alias
constexpr int OFF1_RMAX = OFF1_HIST + 8192;    // f32[152]
constexpr int OFF1_RINV = OFF1_RMAX + 608;     // f32[152]
constexpr int OFF1_SW   = OFF1_RINV + 608;     // u32[16]
constexpr int OFF1_MISC = OFF1_SW + 64;        // s_cnt, sT, sW, sAcc
constexpr int SMEM1     = OFF1_MISC + 16;      // 33,792 B
static_assert(SMEM1 <= 65536, "K1 LDS overflow");

__global__ __launch_bounds__(NT, 8) void k1_select(
    const float* __restrict__ obj_logits,   // B,Q,C
    u64* __restrict__ wsc)                  // B x 256 keys (two ascending 128-lists)
{
    const int blk = blockIdx.x;
    const int b = blk >> 1, h = blk & 1;
    const int row0 = h * HROWS;
    const float* lg = obj_logits + (size_t)b * QC_ + (size_t)row0 * C_;
    const int tid = threadIdx.x;

    __shared__ __align__(16) u8 sm[SMEM1];
    u16*   p16    = (u16*)(sm + OFF1_P16);
    u32*   hist   = (u32*)(sm + OFF1_HIST);
    u64*   cand   = (u64*)(sm + OFF1_HIST);
    float* rowmax = (float*)(sm + OFF1_RMAX);
    float* rinv   = (float*)(sm + OFF1_RINV);
    u32*   swsum  = (u32*)(sm + OFF1_SW);
    u32*   s_cnt  = (u32*)(sm + OFF1_MISC);
    int*   sT     = (int*)(sm + OFF1_MISC + 4);
    int*   sW     = (int*)(sm + OFF1_MISC + 8);
    u32*   sAcc   = (u32*)(sm + OFF1_MISC + 12);

    for (int i = tid; i < NB; i += NT) hist[i] = 0;
    if (tid == 0) *s_cnt = 0;
    __syncthreads();

    // ---- Phase 1 (R5 pattern): coalesced 32-lane-group softmax + p16 + hist ----
    {
        int g = tid >> 5, l = tid & 31;
        bool have2 = (l < C_ - 64);   // l < 17
        for (int q = g; q < HROWS; q += 32) {
            const float* row = lg + q * C_;
            float v0 = row[l], v1 = row[l + 32];
            float v2 = have2 ? row[l + 64] : -INFINITY;
            float m = fmaxf(fmaxf(v0, v1), v2);
            for (int off = 16; off; off >>= 1) m = fmaxf(m, __shfl_xor(m, off, 64));
            float e0 = __expf(v0 - m), e1 = __expf(v1 - m);
            float e2 = have2 ? __expf(v2 - m) : 0.f;
            float s = e0 + e1 + e2;
            for (int off = 16; off; off >>= 1) s += __shfl_xor(s, off, 64);
            float ri = 1.f / s;
            u32 b0 = __float_as_uint(e0 * ri), b1 = __float_as_uint(e1 * ri);
            p16[q * C_ + l]      = (u16)(b0 >> 16);
            p16[q * C_ + l + 32] = (u16)(b1 >> 16);
            atomicAdd(&hist[b0 >> 21], 1u);
            atomicAdd(&hist[b1 >> 21], 1u);
            if (have2) {
                u32 b2 = __float_as_uint(e2 * ri);
                p16[q * C_ + l + 64] = (u16)(b2 >> 16);
                atomicAdd(&hist[b2 >> 21], 1u);
            }
            if (l == 0) { rowmax[q] = m; rinv[q] = ri; }
        }
    }
    __syncthreads();

    // ---- Phase 3: threshold bin T for top-128 (two-level shfl suffix-scan) ----
    u32 my_c, my_suf;
    {
        my_c = hist[2 * tid] + hist[2 * tid + 1];
        my_suf = my_c;
        #pragma unroll
        for (int off = 1; off < 64; off <<= 1) {
            u32 o = (u32)__shfl_down((int)my_suf, off, 64);
            my_suf += ((tid & 63) + off < 64) ? o : 0;
        }
        if ((tid & 63) == 0) swsum[tid >> 6] = my_suf;
    }
    __syncthreads();
    if (tid < 16) {
        u32 sufW = swsum[tid];
        #pragma unroll
        for (int off = 1; off < 16; off <<= 1) {
            u32 o = (u32)__shfl_down((int)sufW, off, 64);
            sufW += (tid + off < 16) ? o : 0;
        }
        u32 nxt = (u32)__shfl_down((int)sufW, 1, 64);
        if (tid == 15) nxt = 0;
        if (sufW >= (u32)TOPH && nxt < (u32)TOPH) { *sW = tid; *sAcc = nxt; }
    }
    __syncthreads();
    if ((tid >> 6) == *sW) {
        u32 above = *sAcc + (my_suf - my_c);
        if (above < (u32)TOPH && above + my_c >= (u32)TOPH) {
            u32 acc = above + hist[2 * tid + 1];
            *sT = (acc >= (u32)TOPH) ? (2 * tid + 1) : (2 * tid);
        }
    }
    __syncthreads();
    const int T = *sT;
    __syncthreads();   // hist reads done; cand may alias

    // ---- Phase 4: scan p16; exact keys recomputed only for candidates ----
    for (int i = tid; i < HQC; i += NT) {
        u32 pb = p16[i];
        if ((int)(pb >> 5) >= T) {
            u32 pos = atomicAdd(s_cnt, 1u);
            if (pos < (u32)CAP) {
                int q = i / C_;
                float p = __expf(lg[i] - rowmax[q]) * rinv[q];  // bit-identical to phase 1
                cand[pos] = ((u64)__float_as_uint(p) << 32) | (u32)(~(row0 * C_ + i));
            }
        }
    }
    __syncthreads();
    int ncand = (int)*s_cnt;
    if (ncand > CAP) ncand = CAP;

    u64* outp = wsc + (size_t)b * 256 + h * TOPH;

    auto cswap = [](u64& a, u64& bb, bool up) {
        if ((a > bb) == up) { u64 t = a; a = bb; bb = t; }
    };

    if (ncand <= 256) {
        // ---- register bitonic-256 on wave 0, zero barriers ----
        if (tid < 64) {
            u64 v0 = (tid < ncand) ? cand[tid] : 0ull;
            u64 v1 = (64 + tid < ncand) ? cand[64 + tid] : 0ull;
            u64 v2 = (128 + tid < ncand) ? cand[128 + tid] : 0ull;
            u64 v3 = (192 + tid < ncand) ? cand[192 + tid] : 0ull;
            for (int k = 2; k <= 256; k <<= 1) {
                for (int j = k >> 1; j > 0; j >>= 1) {
                    if (j == 128) {
                        cswap(v0, v2, true);
                        cswap(v1, v3, true);
                    } else if (j == 64) {
                        cswap(v0, v1, true);
                        cswap(v2, v3, (k == 256));
                    } else {
                        auto step = [&](u64& v, int ebase) {
                            u64 pv = shfl_xor_u64(v, j);
                            int e = ebase + tid;
                            bool up = ((e & k) == 0);
                            bool lower = ((e & j) == 0);
                            u64 mn = v < pv ? v : pv;
                            u64 mx = v < pv ? pv : v;
                            v = (lower == up) ? mn : mx;
                        };
                        step(v0, 0); step(v1, 64); step(v2, 128); step(v3, 192);
                    }
                }
            }
            // ascending; top-128 = elements 128..255 -> outp ascending
            outp[tid]      = v2;   // e = 128+tid
            outp[64 + tid] = v3;   // e = 192+tid
        }
    } else {
        // ---- LDS bitonic-1024 fallback (rare) ----
        for (int e = tid; e < CAP; e += NT)
            if (e >= ncand) cand[e] = 0;
        __syncthreads();
        for (int k = 2; k <= CAP; k <<= 1) {
            for (int j = k >> 1; j > 0; j >>= 1) {
                int e = tid, partner = e ^ j;
                if (partner > e) {
                    u64 a = cand[e], bb = cand[partner];
                    bool up = ((e & k) == 0);
                    if ((a > bb) == up) { cand[e] = bb; cand[partner] = a; }
                }
                __syncthreads();
            }
        }
        if (tid < TOPH) outp[tid] = cand[CAP - TOPH + tid];   // ascending top-128
    }
}

// =====================================================================
// K2: grid 256, NT 1024. Register bitonic-MERGE of two sorted 128-lists
// (9 steps, wave 0, zero barriers), then R5 tail verbatim.
// =====================================================================
constexpr int OFF_HS   = 0;                 // f32[11700]
constexpr int OFF_BSUB = 46800;             // f32[100][4]
constexpr int OFF_BOBJ = OFF_BSUB + 1600;   // f32[100][4]
constexpr int OFF_SUPR = OFF_BOBJ + 1600;   // u32[100][4]
constexpr int OFF_SELV = OFF_SUPR + 1600;   // f32[100]
constexpr int OFF_SELI = OFF_SELV + 400;    // u32[100]
constexpr int OFF_MAXB = OFF_SELI + 400;    // u32[100]
constexpr int OFF_ORD  = OFF_MAXB + 400;    // u8[100] pad 104
constexpr int OFF_MISC = OFF_ORD + 104;     // skeep[4], keep_bits[4]
constexpr int SMEM2    = OFF_MISC + 32;     // 52,936
static_assert(SMEM2 <= 65536, "K2 LDS overflow");

__global__ __launch_bounds__(NT) void k2_finish(
    const u64*  __restrict__ wsc,           // B x 256 keys
    const float* __restrict__ verb_logits,  // B,Q,V
    const float* __restrict__ sub_boxes_in, // B,Q,4
    const float* __restrict__ obj_boxes_in, // B,Q,4
    const float* __restrict__ cm,           // V,C
    const int*   __restrict__ tsizes,       // B,2 (h,w)
    float* __restrict__ out)
{
    const int b = blockIdx.x;
    const int tid = threadIdx.x;

    __shared__ __align__(16) u8 smem[SMEM2];
    float* hs      = (float*)(smem + OFF_HS);
    float (*bsub)[4]   = (float(*)[4])(smem + OFF_BSUB);
    float (*bobj)[4]   = (float(*)[4])(smem + OFF_BOBJ);
    u32   (*suprow)[4] = (u32(*)[4])(smem + OFF_SUPR);
    float* sel_val = (float*)(smem + OFF_SELV);
    u32*   sel_idx = (u32*)(smem + OFF_SELI);
    u32*   maxbits = (u32*)(smem + OFF_MAXB);
    u8*    order8  = (u8*)(smem + OFF_ORD);
    u32*   skeep     = (u32*)(smem + OFF_MISC);
    u32*   keep_bits = (u32*)(smem + OFF_MISC + 16);

    // ---- merge: halves ascending; load half1 reversed -> bitonic sequence ----
    if (tid < 64) {
        const u64* base = wsc + (size_t)b * 256;
        u64 v0 = base[tid];          // e = tid        (half0 asc)
        u64 v1 = base[64 + tid];     // e = 64+tid
        u64 v2 = base[255 - tid];    // e = 128+tid    (half1 desc)
        u64 v3 = base[191 - tid];    // e = 192+tid
        auto cswap = [](u64& a, u64& bb) {
            if (a > bb) { u64 t = a; a = bb; bb = t; }
        };
        cswap(v0, v2); cswap(v1, v3);    // j = 128
        cswap(v0, v1); cswap(v2, v3);    // j = 64
        for (int j = 32; j > 0; j >>= 1) {
            auto step = [&](u64& v) {
                u64 pv = shfl_xor_u64(v, j);
                bool lower = ((tid & j) == 0);
                u64 mn = v < pv ? v : pv;
                u64 mx = v < pv ? pv : v;
                v = lower ? mn : mx;
            };
            step(v0); step(v1); step(v2); step(v3);
        }
        // ascending over 256; top-100 = e in [156,255], rank = 255-e
        int e2 = 128 + tid;
        if (e2 >= 156) {
            int t = 255 - e2;
            u32 idx = ~(u32)v2; if (idx >= (u32)QC_) idx = 0;
            sel_val[t] = __uint_as_float((u32)(v2 >> 32));
            sel_idx[t] = idx;
        }
        int t3 = 63 - tid;   // e = 192+tid
        u32 idx3 = ~(u32)v3; if (idx3 >= (u32)QC_) idx3 = 0;
        sel_val[t3] = __uint_as_float((u32)(v3 >> 32));
        sel_idx[t3] = idx3;
    }
    if (tid >= 128 && tid < 132) keep_bits[tid - 128] = 0;
    __syncthreads();

    // ---- gather + scale boxes; init NMS state ----
    if (tid < K_) {
        int idx = (int)sel_idx[tid];
        int q = idx / C_;
        float iw = (float)tsizes[b * 2 + 1];
        float ih = (float)tsizes[b * 2 + 0];
        float4 sb = ((const float4*)sub_boxes_in)[(size_t)b * Q_ + q];
        float4 ob = ((const float4*)obj_boxes_in)[(size_t)b * Q_ + q];
        bsub[tid][0] = (sb.x - 0.5f * sb.z) * iw; bsub[tid][1] = (sb.y - 0.5f * sb.w) * ih;
        bsub[tid][2] = (sb.x + 0.5f * sb.z) * iw; bsub[tid][3] = (sb.y + 0.5f * sb.w) * ih;
        bobj[tid][0] = (ob.x - 0.5f * ob.z) * iw; bobj[tid][1] = (ob.y - 0.5f * ob.w) * ih;
        bobj[tid][2] = (ob.x + 0.5f * ob.z) * iw; bobj[tid][3] = (ob.y + 0.5f * ob.w) * ih;
        suprow[tid][0] = 0; suprow[tid][1] = 0; suprow[tid][2] = 0; suprow[tid][3] = 0;
    }
    __syncthreads();

    // ---- hoi scores into hs ----
    for (int f = tid; f < KV_; f += NT) {
        int r = f / V_, v = f - r * V_;
        int idx = (int)sel_idx[r];
        int q = idx / C_, lab = idx - q * C_;
        float x = verb_logits[((size_t)b * Q_ + q) * V_ + v];
        float s = 1.f / (1.f + __expf(-x));
        hs[f] = s * sel_val[r] * cm[v * C_ + lab];
    }
    __syncthreads();

    // ---- per-row max, 8 lanes/row ----
    if (tid < 800) {
        int r = tid >> 3, j = tid & 7;
        float m = 0.f;
        for (int k = 0; k < 15; k++) {
            int v = j * 15 + k;
            if (v < V_) m = fmaxf(m, hs[r * V_ + v]);
        }
        for (int off = 4; off; off >>= 1) m = fmaxf(m, __shfl_xor(m, off, 64));
        if (j == 0) maxbits[r] = __float_as_uint(m);
    }
    __syncthreads();

    // ---- stable descending rank, 8 lanes/row ----
    if (tid < 800) {
        int r = tid >> 3, j = tid & 7;
        u64 kr = ((u64)maxbits[r] << 32) | (u32)(~r);
        int rank = 0;
        for (int k = 0; k < 13; k++) {
            int jj = j * 13 + k;
            if (jj < K_) {
                u64 kj = ((u64)maxbits[jj] << 32) | (u32)(~jj);
                rank += (kj > kr) ? 1 : 0;
            }
        }
        for (int off = 4; off; off >>= 1) rank += __shfl_xor(rank, off, 64);
        if (j == 0) order8[rank] = (u8)r;
    }
    __syncthreads();

    // ---- 100x100 suppression bitmatrix in sorted space ----
    for (int e = tid; e < K_ * K_; e += NT) {
        int i = e / K_, j = e - i * K_;
        if (j > i) {
            int ri = order8[i], rj = order8[j];
            u32 li = sel_idx[ri] % (u32)C_, lj = sel_idx[rj] % (u32)C_;
            if (li == lj) {
                float o = iou1(bsub[ri], bsub[rj]) * iou1(bobj[ri], bobj[rj]);
                if (o > 0.5f)
                    atomicOr(&suprow[i][j >> 5], 1u << (j & 31));
            }
        }
    }
    __syncthreads();

    // ---- greedy scan: single wave, register-resident ----
    if (tid < 64) {
        u32 ra0 = suprow[tid][0], ra1 = suprow[tid][1], ra2 = suprow[tid][2], ra3 = suprow[tid][3];
        u32 rb0 = 0, rb1 = 0, rb2 = 0, rb3 = 0;
        if (tid < K_ - 64) {
            rb0 = suprow[tid + 64][0]; rb1 = suprow[tid + 64][1];
            rb2 = suprow[tid + 64][2]; rb3 = suprow[tid + 64][3];
        }
        u32 acc[4] = {0, 0, 0, 0};
        u32 km[4]  = {0, 0, 0, 0};
        #pragma unroll
        for (int i = 0; i < K_; i++) {
            u32 r0, r1, r2, r3;
            if (i < 64) {
                r0 = (u32)__shfl((int)ra0, i, 64); r1 = (u32)__shfl((int)ra1, i, 64);
                r2 = (u32)__shfl((int)ra2, i, 64); r3 = (u32)__shfl((int)ra3, i, 64);
            } else {
                r0 = (u32)__shfl((int)rb0, i - 64, 64); r1 = (u32)__shfl((int)rb1, i - 64, 64);
                r2 = (u32)__shfl((int)rb2, i - 64, 64); r3 = (u32)__shfl((int)rb3, i - 64, 64);
            }
            bool sup_i = (acc[i >> 5] >> (i & 31)) & 1u;
            if (!sup_i) {
                km[i >> 5] |= 1u << (i & 31);
                acc[0] |= r0; acc[1] |= r1; acc[2] |= r2; acc[3] |= r3;
            }
        }
        if (tid == 0) { skeep[0] = km[0]; skeep[1] = km[1]; skeep[2] = km[2]; skeep[3] = km[3]; }
    }
    __syncthreads();
    if (tid < K_) {
        if ((skeep[tid >> 5] >> (tid & 31)) & 1u) {
            int r = order8[tid];
            atomicOr(&keep_bits[r >> 5], 1u << (r & 31));
        }
    }
    __syncthreads();

    // ---- write outputs (float32, concatenated in return order) ----
    float* o0 = out;                                   // final_scores B,K,V
    float* o1 = out + (size_t)B_ * KV_;                // topk_values  B,K
    float* o2 = o1 + (size_t)B_ * K_;                  // obj_labels   B,K
    float* o3 = o2 + (size_t)B_ * K_;                  // sub_boxes    B,K,4
    float* o4 = o3 + (size_t)B_ * K_ * 4;              // obj_boxes    B,K,4
    float* o5 = o4 + (size_t)B_ * K_ * 4;              // keep         B,K

    for (int f = tid; f < KV_; f += NT) {
        int r = f / V_;
        bool kp = (keep_bits[r >> 5] >> (r & 31)) & 1u;
        o0[(size_t)b * KV_ + f] = kp ? hs[f] : 0.f;
    }
    if (tid < K_) {
        bool kp = (keep_bits[tid >> 5] >> (tid & 31)) & 1u;
        o1[(size_t)b * K_ + tid] = sel_val[tid];
        o2[(size_t)b * K_ + tid] = (float)(sel_idx[tid] % (u32)C_);
        o5[(size_t)b * K_ + tid] = kp ? 1.f : 0.f;
    }
    if (tid < K_ * 4) {
        int r = tid >> 2, k = tid & 3;
        o3[((size_t)b * K_) * 4 + tid] = bsub[r][k];
        o4[((size_t)b * K_) * 4 + tid] = bobj[r][k];
    }
}

extern "C" void kernel_launch(void* const* d_in, const int* in_sizes, int n_in,
                              void* d_out, int out_size, void* d_ws, size_t ws_size,
                              hipStream_t stream) {
    const float* obj_logits  = (const float*)d_in[0];
    const float* verb_logits = (const float*)d_in[1];
    const float* sub_boxes   = (const float*)d_in[2];
    const float* obj_boxes   = (const float*)d_in[3];
    const float* cm          = (const float*)d_in[4];
    const int*   ts          = (const int*)d_in[5];
    u64* wsc = (u64*)d_ws;    // needs B_*256*8 = 512 KiB

    hipLaunchKernelGGL(k1_select, dim3(B_ * 2), dim3(NT), 0, stream,
                       obj_logits, wsc);
    hipLaunchKernelGGL(k2_finish, dim3(B_), dim3(NT), 0, stream,
                       wsc, verb_logits, sub_boxes, obj_boxes, cm, ts,
                       (float*)d_out);
}

// Round 9
// 143.748 us; speedup vs baseline: 1.2534x; 1.0214x over previous
//
#include <hip/hip_runtime.h>
#include <cmath>

#pragma clang fp contract(off)

#define NT 1024
constexpr int B_ = 256, Q_ = 300, C_ = 81, V_ = 117, K_ = 100;
constexpr int QC_ = Q_ * C_;   // 24300
constexpr int KV_ = K_ * V_;   // 11700
constexpr int NB  = 2048;      // histogram bins = prob float-bits >> 21
constexpr int CAP = 1024;      // LDS candidate buffer (fallback sort size)

using u32 = unsigned int;
using u64 = unsigned long long;
using u16 = unsigned short;
using u8  = unsigned char;

// ---- LDS layout (lifetime-aliased; 65,344 B <= 64 KiB) — R5 layout, hs removed ----
constexpr int OFF_P16  = 0;                 // u16[24300]=48600 (dead after phase 4)
constexpr int OFF_HIST = 48600;             // u32[2048]=8192 | cand u64[1024] (after threshold)
constexpr int OFF_RMAX = OFF_HIST + 8192;   // f32[300]
constexpr int OFF_RINV = OFF_RMAX + 1200;   // f32[300]
constexpr int OFF_BSUB = OFF_RINV + 1200;   // f32[100][4] | swsum u32[16] (phase 3)
constexpr int OFF_BOBJ = OFF_BSUB + 1600;   // f32[100][4]
constexpr int OFF_SUPR = OFF_BOBJ + 1600;   // u32[100][4]
constexpr int OFF_SELV = OFF_SUPR + 1600;   // f32[100]
constexpr int OFF_SELI = OFF_SELV + 400;    // u32[100]
constexpr int OFF_MAXB = OFF_SELI + 400;    // u32[100]
constexpr int OFF_ORD  = OFF_MAXB + 400;    // u8[100] (pad 104)
constexpr int OFF_MISC = OFF_ORD + 104;     // skeep[4], keep_bits[4], s_cnt, sT, sW, sAcc
constexpr int SMEM_SZ  = OFF_MISC + 48;     // 65,344
static_assert(SMEM_SZ <= 65536, "LDS overflow");

__device__ __forceinline__ u64 shfl_xor_u64(u64 v, int mask) {
    u32 lo = (u32)v, hi = (u32)(v >> 32);
    lo = (u32)__shfl_xor((int)lo, mask, 64);
    hi = (u32)__shfl_xor((int)hi, mask, 64);
    return ((u64)hi << 32) | lo;
}

__device__ __forceinline__ float iou1(const float* a, const float* b) {
    float areaA = (a[2] - a[0] + 1.f) * (a[3] - a[1] + 1.f);
    float areaB = (b[2] - b[0] + 1.f) * (b[3] - b[1] + 1.f);
    float xx1 = fmaxf(a[0], b[0]);
    float yy1 = fmaxf(a[1], b[1]);
    float xx2 = fminf(a[2], b[2]);
    float yy2 = fminf(a[3], b[3]);
    float w = fmaxf(0.f, xx2 - xx1 + 1.f);
    float h = fmaxf(0.f, yy2 - yy1 + 1.f);
    float inter = w * h;
    return inter / (areaA + areaB - inter);
}

__global__ __launch_bounds__(NT) void hoi_kernel(
    const float* __restrict__ obj_logits,   // B,Q,C
    const float* __restrict__ verb_logits,  // B,Q,V
    const float* __restrict__ sub_boxes_in, // B,Q,4
    const float* __restrict__ obj_boxes_in, // B,Q,4
    const float* __restrict__ cm,           // V,C
    const int*   __restrict__ tsizes,       // B,2 (h,w)
    float* __restrict__ out)
{
    const int b = blockIdx.x;
    const int tid = threadIdx.x;

    __shared__ __align__(16) u8 smem[SMEM_SZ];
    u16*   p16     = (u16*)(smem + OFF_P16);
    u32*   hist    = (u32*)(smem + OFF_HIST);
    u64*   cand    = (u64*)(smem + OFF_HIST);
    float* rowmax  = (float*)(smem + OFF_RMAX);
    float* rinv    = (float*)(smem + OFF_RINV);
    float (*bsub)[4]   = (float(*)[4])(smem + OFF_BSUB);
    float (*bobj)[4]   = (float(*)[4])(smem + OFF_BOBJ);
    u32   (*suprow)[4] = (u32(*)[4])(smem + OFF_SUPR);
    float* sel_val = (float*)(smem + OFF_SELV);
    u32*   sel_idx = (u32*)(smem + OFF_SELI);
    u32*   maxbits = (u32*)(smem + OFF_MAXB);
    u8*    order8  = (u8*)(smem + OFF_ORD);
    u32*   skeep     = (u32*)(smem + OFF_MISC);
    u32*   keep_bits = (u32*)(smem + OFF_MISC + 16);
    u32*   s_cnt     = (u32*)(smem + OFF_MISC + 32);
    int*   sT        = (int*)(smem + OFF_MISC + 36);
    int*   sW        = (int*)(smem + OFF_MISC + 40);
    u32*   sAcc      = (u32*)(smem + OFF_MISC + 44);
    u32*   swsum   = (u32*)(smem + OFF_BSUB);   // phase-3 scratch
    u64*   wred    = (u64*)(smem + OFF_BOBJ);   // 5c scratch
    u64*   s_prev  = (u64*)(smem + OFF_SUPR);   // 5c scratch

    const float* lg = obj_logits + (size_t)b * QC_;

    // output pointers (float32, concatenated in return order)
    float* o0 = out;                                   // final_scores B,K,V
    float* o1 = out + (size_t)B_ * KV_;                // topk_values  B,K
    float* o2 = o1 + (size_t)B_ * K_;                  // obj_labels   B,K
    float* o3 = o2 + (size_t)B_ * K_;                  // sub_boxes    B,K,4
    float* o4 = o3 + (size_t)B_ * K_ * 4;              // obj_boxes    B,K,4
    float* o5 = o4 + (size_t)B_ * K_ * 4;              // keep         B,K

    for (int i = tid; i < NB; i += NT) hist[i] = 0;
    if (tid == 0) *s_cnt = 0;
    __syncthreads();

    // ---- Phase 1 (R5 form): coalesced 32-lane-group softmax + p16 cache + hist ----
    {
        int g = tid >> 5, l = tid & 31;
        bool have2 = (l < C_ - 64);   // l < 17
        for (int q = g; q < Q_; q += 32) {
            const float* row = lg + q * C_;
            float v0 = row[l], v1 = row[l + 32];
            float v2 = have2 ? row[l + 64] : -INFINITY;
            float m = fmaxf(fmaxf(v0, v1), v2);
            for (int off = 16; off; off >>= 1) m = fmaxf(m, __shfl_xor(m, off, 64));
            float e0 = __expf(v0 - m), e1 = __expf(v1 - m);
            float e2 = have2 ? __expf(v2 - m) : 0.f;
            float s = e0 + e1 + e2;
            for (int off = 16; off; off >>= 1) s += __shfl_xor(s, off, 64);
            float ri = 1.f / s;
            u32 b0 = __float_as_uint(e0 * ri), b1 = __float_as_uint(e1 * ri);
            p16[q * C_ + l]      = (u16)(b0 >> 16);
            p16[q * C_ + l + 32] = (u16)(b1 >> 16);
            atomicAdd(&hist[b0 >> 21], 1u);
            atomicAdd(&hist[b1 >> 21], 1u);
            if (have2) {
                u32 b2 = __float_as_uint(e2 * ri);
                p16[q * C_ + l + 64] = (u16)(b2 >> 16);
                atomicAdd(&hist[b2 >> 21], 1u);
            }
            if (l == 0) { rowmax[q] = m; rinv[q] = ri; }
        }
    }
    __syncthreads();

    // ---- Phase 3: threshold bin T via two-level shfl suffix-scan ----
    u32 my_c, my_suf;
    {
        my_c = hist[2 * tid] + hist[2 * tid + 1];
        my_suf = my_c;
        #pragma unroll
        for (int off = 1; off < 64; off <<= 1) {
            u32 o = (u32)__shfl_down((int)my_suf, off, 64);
            my_suf += ((tid & 63) + off < 64) ? o : 0;
        }
        if ((tid & 63) == 0) swsum[tid >> 6] = my_suf;
    }
    __syncthreads();
    if (tid < 16) {
        u32 sufW = swsum[tid];
        #pragma unroll
        for (int off = 1; off < 16; off <<= 1) {
            u32 o = (u32)__shfl_down((int)sufW, off, 64);
            sufW += (tid + off < 16) ? o : 0;
        }
        u32 nxt = (u32)__shfl_down((int)sufW, 1, 64);
        if (tid == 15) nxt = 0;
        if (sufW >= (u32)K_ && nxt < (u32)K_) { *sW = tid; *sAcc = nxt; }
    }
    __syncthreads();
    if ((tid >> 6) == *sW) {
        u32 above = *sAcc + (my_suf - my_c);
        if (above < (u32)K_ && above + my_c >= (u32)K_) {
            u32 acc = above + hist[2 * tid + 1];
            *sT = (acc >= (u32)K_) ? (2 * tid + 1) : (2 * tid);
        }
    }
    __syncthreads();
    const int T = *sT;
    __syncthreads();   // hist reads done; cand may alias

    // ---- Phase 4: scan p16; exact keys recomputed only for candidates ----
    for (int i = tid; i < QC_; i += NT) {
        u32 pb = p16[i];
        if ((int)(pb >> 5) >= T) {
            u32 pos = atomicAdd(s_cnt, 1u);
            if (pos < (u32)CAP) {
                int q = i / C_;
                float p = __expf(lg[i] - rowmax[q]) * rinv[q];  // bit-identical to phase 1
                cand[pos] = ((u64)__float_as_uint(p) << 32) | (u32)(~i);
            }
        }
    }
    __syncthreads();
    const int ncand = (int)*s_cnt;

    auto cswap = [](u64& a, u64& bb, bool up) {
        if ((a > bb) == up) { u64 t = a; a = bb; bb = t; }
    };

    if (ncand <= 256) {
        // ---- Phase 5a: register-resident bitonic-256 on wave 0 — zero barriers ----
        if (tid < 64) {
            u64 v0 = (tid < ncand) ? cand[tid] : 0ull;
            u64 v1 = (64 + tid < ncand) ? cand[64 + tid] : 0ull;
            u64 v2 = (128 + tid < ncand) ? cand[128 + tid] : 0ull;
            u64 v3 = (192 + tid < ncand) ? cand[192 + tid] : 0ull;
            for (int k = 2; k <= 256; k <<= 1) {
                for (int j = k >> 1; j > 0; j >>= 1) {
                    if (j == 128) {
                        cswap(v0, v2, true);
                        cswap(v1, v3, true);
                    } else if (j == 64) {
                        cswap(v0, v1, true);
                        cswap(v2, v3, (k == 256));
                    } else {
                        auto step = [&](u64& v, int ebase) {
                            u64 pv = shfl_xor_u64(v, j);
                            int e = ebase + tid;
                            bool up = ((e & k) == 0);
                            bool lower = ((e & j) == 0);
                            u64 mn = v < pv ? v : pv;
                            u64 mx = v < pv ? pv : v;
                            v = (lower == up) ? mn : mx;
                        };
                        step(v0, 0); step(v1, 64); step(v2, 128); step(v3, 192);
                    }
                }
            }
            int e2 = 128 + tid;
            if (e2 >= 156) {
                int t = 255 - e2;
                sel_val[t] = __uint_as_float((u32)(v2 >> 32));
                sel_idx[t] = ~(u32)v2;
            }
            int t3 = 255 - (192 + tid);
            sel_val[t3] = __uint_as_float((u32)(v3 >> 32));
            sel_idx[t3] = ~(u32)v3;
        }
    } else if (ncand <= CAP) {
        // ---- Phase 5b: LDS bitonic-1024 fallback ----
        for (int e = tid; e < CAP; e += NT)
            if (e >= ncand) cand[e] = 0;
        __syncthreads();
        for (int k = 2; k <= CAP; k <<= 1) {
            for (int j = k >> 1; j > 0; j >>= 1) {
                int e = tid, partner = e ^ j;
                if (partner > e) {
                    u64 a = cand[e], bb = cand[partner];
                    bool up = ((e & k) == 0);
                    if ((a > bb) == up) { cand[e] = bb; cand[partner] = a; }
                }
                __syncthreads();
            }
        }
        if (tid < K_) {
            u64 m = cand[CAP - 1 - tid];
            sel_val[tid] = __uint_as_float((u32)(m >> 32));
            sel_idx[tid] = ~(u32)m;
        }
    } else {
        // ---- Phase 5c (near-dead): 100-round argmax with strict-less chaining ----
        if (tid == 0) *s_prev = ~0ull;
        __syncthreads();
        for (int r = 0; r < K_; r++) {
            u64 prev = *s_prev;
            u64 local = 0;
            for (int i = tid; i < QC_; i += NT) {
                int q = i / C_;
                float p = __expf(lg[i] - rowmax[q]) * rinv[q];
                u64 key = ((u64)__float_as_uint(p) << 32) | (u32)(~i);
                if (key < prev && key > local) local = key;
            }
            for (int off = 32; off > 0; off >>= 1) {
                u64 o = shfl_xor_u64(local, off);
                if (o > local) local = o;
            }
            if ((tid & 63) == 0) wred[tid >> 6] = local;
            __syncthreads();
            if (tid == 0) {
                u64 m = wred[0];
                for (int wv = 1; wv < 16; wv++) if (wred[wv] > m) m = wred[wv];
                *s_prev = m;
                u32 idx = ~(u32)m;
                if (idx >= (u32)QC_) idx = 0;
                sel_val[r] = __uint_as_float((u32)(m >> 32));
                sel_idx[r] = idx;
            }
            __syncthreads();
        }
    }
    __syncthreads();   // sel_* visible; p16/hist/cand/rowstats dead

    // ---- Phase 5.5: gather + scale boxes; init NMS state ----
    if (tid < K_) {
        int idx = (int)sel_idx[tid];
        int q = idx / C_;
        float iw = (float)tsizes[b * 2 + 1];
        float ih = (float)tsizes[b * 2 + 0];
        float4 sb = ((const float4*)sub_boxes_in)[(size_t)b * Q_ + q];
        float4 ob = ((const float4*)obj_boxes_in)[(size_t)b * Q_ + q];
        bsub[tid][0] = (sb.x - 0.5f * sb.z) * iw; bsub[tid][1] = (sb.y - 0.5f * sb.w) * ih;
        bsub[tid][2] = (sb.x + 0.5f * sb.z) * iw; bsub[tid][3] = (sb.y + 0.5f * sb.w) * ih;
        bobj[tid][0] = (ob.x - 0.5f * ob.z) * iw; bobj[tid][1] = (ob.y - 0.5f * ob.w) * ih;
        bobj[tid][2] = (ob.x + 0.5f * ob.z) * iw; bobj[tid][3] = (ob.y + 0.5f * ob.w) * ih;
        suprow[tid][0] = 0; suprow[tid][1] = 0; suprow[tid][2] = 0; suprow[tid][3] = 0;
    }
    if (tid >= 128 && tid < 132) keep_bits[tid - 128] = 0;
    __syncthreads();

    // ---- Phase 6 (restructured): one wave per row — compute hoi scores, write
    // final_scores DIRECTLY to global, reduce row max in-wave. No hs LDS array,
    // no extra barrier, no integer divides. ----
    {
        int w = tid >> 6, l = tid & 63;
        for (int r = w; r < K_; r += 16) {
            int idx = (int)sel_idx[r];
            int q = idx / C_, lab = idx - q * C_;
            float val = sel_val[r];
            const float* vrow = verb_logits + ((size_t)b * Q_ + q) * V_;
            float* orow = o0 + (size_t)b * KV_ + r * V_;
            float x0 = vrow[l];
            float h0 = (1.f / (1.f + __expf(-x0))) * val * cm[l * C_ + lab];
            orow[l] = h0;
            float h1 = 0.f;
            if (l < V_ - 64) {
                float x1 = vrow[l + 64];
                h1 = (1.f / (1.f + __expf(-x1))) * val * cm[(l + 64) * C_ + lab];
                orow[l + 64] = h1;
            }
            float m = fmaxf(h0, h1);
            for (int off = 32; off; off >>= 1) m = fmaxf(m, __shfl_xor(m, off, 64));
            if (l == 0) maxbits[r] = __float_as_uint(m);
        }
    }
    __syncthreads();

    // ---- Phase 7: stable descending rank, 8 lanes/row ----
    if (tid < 800) {
        int r = tid >> 3, j = tid & 7;
        u64 kr = ((u64)maxbits[r] << 32) | (u32)(~r);
        int rank = 0;
        for (int k = 0; k < 13; k++) {
            int jj = j * 13 + k;
            if (jj < K_) {
                u64 kj = ((u64)maxbits[jj] << 32) | (u32)(~jj);
                rank += (kj > kr) ? 1 : 0;
            }
        }
        for (int off = 4; off; off >>= 1) rank += __shfl_xor(rank, off, 64);
        if (j == 0) order8[rank] = (u8)r;
    }
    __syncthreads();

    // ---- Phase 8a: 100x100 suppression bitmatrix in sorted space ----
    for (int e = tid; e < K_ * K_; e += NT) {
        int i = e / K_, j = e - i * K_;
        if (j > i) {
            int ri = order8[i], rj = order8[j];
            u32 li = sel_idx[ri] % (u32)C_, lj = sel_idx[rj] % (u32)C_;
            if (li == lj) {
                float o = iou1(bsub[ri], bsub[rj]) * iou1(bobj[ri], bobj[rj]);
                if (o > 0.5f)
                    atomicOr(&suprow[i][j >> 5], 1u << (j & 31));
            }
        }
    }
    __syncthreads();

    // ---- Phase 8b: greedy scan — single wave, register-resident ----
    if (tid < 64) {
        u32 ra0 = suprow[tid][0], ra1 = suprow[tid][1], ra2 = suprow[tid][2], ra3 = suprow[tid][3];
        u32 rb0 = 0, rb1 = 0, rb2 = 0, rb3 = 0;
        if (tid < K_ - 64) {
            rb0 = suprow[tid + 64][0]; rb1 = suprow[tid + 64][1];
            rb2 = suprow[tid + 64][2]; rb3 = suprow[tid + 64][3];
        }
        u32 acc[4] = {0, 0, 0, 0};
        u32 km[4]  = {0, 0, 0, 0};
        #pragma unroll
        for (int i = 0; i < K_; i++) {
            u32 r0, r1, r2, r3;
            if (i < 64) {
                r0 = (u32)__shfl((int)ra0, i, 64); r1 = (u32)__shfl((int)ra1, i, 64);
                r2 = (u32)__shfl((int)ra2, i, 64); r3 = (u32)__shfl((int)ra3, i, 64);
            } else {
                r0 = (u32)__shfl((int)rb0, i - 64, 64); r1 = (u32)__shfl((int)rb1, i - 64, 64);
                r2 = (u32)__shfl((int)rb2, i - 64, 64); r3 = (u32)__shfl((int)rb3, i - 64, 64);
            }
            bool sup_i = (acc[i >> 5] >> (i & 31)) & 1u;
            if (!sup_i) {
                km[i >> 5] |= 1u << (i & 31);
                acc[0] |= r0; acc[1] |= r1; acc[2] |= r2; acc[3] |= r3;
            }
        }
        if (tid == 0) { skeep[0] = km[0]; skeep[1] = km[1]; skeep[2] = km[2]; skeep[3] = km[3]; }
    }
    __syncthreads();
    if (tid < K_) {
        if ((skeep[tid >> 5] >> (tid & 31)) & 1u) {
            int r = order8[tid];
            atomicOr(&keep_bits[r >> 5], 1u << (r & 31));
        }
    }
    __syncthreads();

    // ---- Phase 9: zero suppressed rows of o0 (already written); small outputs ----
    {
        int w = tid >> 6, l = tid & 63;
        for (int r = w; r < K_; r += 16) {
            if (!((keep_bits[r >> 5] >> (r & 31)) & 1u)) {
                float* orow = o0 + (size_t)b * KV_ + r * V_;
                orow[l] = 0.f;
                if (l < V_ - 64) orow[l + 64] = 0.f;
            }
        }
    }
    if (tid < K_) {
        bool kp = (keep_bits[tid >> 5] >> (tid & 31)) & 1u;
        o1[(size_t)b * K_ + tid] = sel_val[tid];
        o2[(size_t)b * K_ + tid] = (float)(sel_idx[tid] % (u32)C_);
        o5[(size_t)b * K_ + tid] = kp ? 1.f : 0.f;
    }
    if (tid < K_ * 4) {
        int r = tid >> 2, k = tid & 3;
        o3[((size_t)b * K_) * 4 + tid] = bsub[r][k];
        o4[((size_t)b * K_) * 4 + tid] = bobj[r][k];
    }
}

extern "C" void kernel_launch(void* const* d_in, const int* in_sizes, int n_in,
                              void* d_out, int out_size, void* d_ws, size_t ws_size,
                              hipStream_t stream) {
    const float* obj_logits  = (const float*)d_in[0];
    const float* verb_logits = (const float*)d_in[1];
    const float* sub_boxes   = (const float*)d_in[2];
    const float* obj_boxes   = (const float*)d_in[3];
    const float* cm          = (const float*)d_in[4];
    const int*   ts          = (const int*)d_in[5];
    hipLaunchKernelGGL(hoi_kernel, dim3(B_), dim3(NT), 0, stream,
                       obj_logits, verb_logits, sub_boxes, obj_boxes, cm, ts,
                       (float*)d_out);
}

// Round 10
// 143.467 us; speedup vs baseline: 1.2559x; 1.0020x over previous
//
#include <hip/hip_runtime.h>
#include <cmath>

#pragma clang fp contract(off)

#define NT 1024
constexpr int B_ = 256, Q_ = 300, C_ = 81, V_ = 117, K_ = 100;
constexpr int QC_ = Q_ * C_;   // 24300
constexpr int KV_ = K_ * V_;   // 11700
constexpr int NB  = 2048;      // histogram bins = prob float-bits >> 21
constexpr int CAP = 1024;      // LDS candidate buffer (fallback sort size)

using u32 = unsigned int;
using u64 = unsigned long long;
using u16 = unsigned short;
using u8  = unsigned char;

// ---- LDS layout (lifetime-aliased; 65,344 B <= 64 KiB) ----
constexpr int OFF_P16  = 0;                 // u16[24300]=48600 (dead after phase 4)
constexpr int OFF_HIST = 48600;             // u32[2048]=8192 | cand u64[1024] (after threshold)
constexpr int OFF_RMAX = OFF_HIST + 8192;   // f32[300]
constexpr int OFF_RINV = OFF_RMAX + 1200;   // f32[300]
constexpr int OFF_BSUB = OFF_RINV + 1200;   // f32[100][4]
constexpr int OFF_BOBJ = OFF_BSUB + 1600;   // f32[100][4] | wred u64[16] (5c scratch)
constexpr int OFF_SUPR = OFF_BOBJ + 1600;   // u32[100][4]
constexpr int OFF_SELV = OFF_SUPR + 1600;   // f32[100]
constexpr int OFF_SELI = OFF_SELV + 400;    // u32[100]
constexpr int OFF_MAXB = OFF_SELI + 400;    // u32[100]
constexpr int OFF_ORD  = OFF_MAXB + 400;    // u8[100] (pad 104)
constexpr int OFF_MISC = OFF_ORD + 104;     // skeep[4]@0, keep_bits[4]@16, s_cnt@32, sT@36, s_prev u64@40
constexpr int SMEM_SZ  = OFF_MISC + 48;     // 65,344
static_assert(SMEM_SZ <= 65536, "LDS overflow");
static_assert((OFF_MISC + 40) % 8 == 0, "s_prev align");

__device__ __forceinline__ u64 shfl_xor_u64(u64 v, int mask) {
    u32 lo = (u32)v, hi = (u32)(v >> 32);
    lo = (u32)__shfl_xor((int)lo, mask, 64);
    hi = (u32)__shfl_xor((int)hi, mask, 64);
    return ((u64)hi << 32) | lo;
}

__device__ __forceinline__ float iou1(const float* a, const float* b) {
    float areaA = (a[2] - a[0] + 1.f) * (a[3] - a[1] + 1.f);
    float areaB = (b[2] - b[0] + 1.f) * (b[3] - b[1] + 1.f);
    float xx1 = fmaxf(a[0], b[0]);
    float yy1 = fmaxf(a[1], b[1]);
    float xx2 = fminf(a[2], b[2]);
    float yy2 = fminf(a[3], b[3]);
    float w = fmaxf(0.f, xx2 - xx1 + 1.f);
    float h = fmaxf(0.f, yy2 - yy1 + 1.f);
    float inter = w * h;
    return inter / (areaA + areaB - inter);
}

__global__ __launch_bounds__(NT) void hoi_kernel(
    const float* __restrict__ obj_logits,   // B,Q,C
    const float* __restrict__ verb_logits,  // B,Q,V
    const float* __restrict__ sub_boxes_in, // B,Q,4
    const float* __restrict__ obj_boxes_in, // B,Q,4
    const float* __restrict__ cm,           // V,C
    const int*   __restrict__ tsizes,       // B,2 (h,w)
    float* __restrict__ out)
{
    const int b = blockIdx.x;
    const int tid = threadIdx.x;

    __shared__ __align__(16) u8 smem[SMEM_SZ];
    u16*   p16     = (u16*)(smem + OFF_P16);
    u32*   hist    = (u32*)(smem + OFF_HIST);
    u64*   cand    = (u64*)(smem + OFF_HIST);
    float* rowmax  = (float*)(smem + OFF_RMAX);
    float* rinv    = (float*)(smem + OFF_RINV);
    float (*bsub)[4]   = (float(*)[4])(smem + OFF_BSUB);
    float (*bobj)[4]   = (float(*)[4])(smem + OFF_BOBJ);
    u32   (*suprow)[4] = (u32(*)[4])(smem + OFF_SUPR);
    float* sel_val = (float*)(smem + OFF_SELV);
    u32*   sel_idx = (u32*)(smem + OFF_SELI);
    u32*   maxbits = (u32*)(smem + OFF_MAXB);
    u8*    order8  = (u8*)(smem + OFF_ORD);
    u32*   skeep     = (u32*)(smem + OFF_MISC);
    u32*   keep_bits = (u32*)(smem + OFF_MISC + 16);
    u32*   s_cnt     = (u32*)(smem + OFF_MISC + 32);
    int*   sT        = (int*)(smem + OFF_MISC + 36);
    u64*   s_prev    = (u64*)(smem + OFF_MISC + 40);
    u64*   wred      = (u64*)(smem + OFF_BOBJ);   // 5c scratch (bobj written later)

    const float* lg = obj_logits + (size_t)b * QC_;

    // output pointers (float32, concatenated in return order)
    float* o0 = out;                                   // final_scores B,K,V
    float* o1 = out + (size_t)B_ * KV_;                // topk_values  B,K
    float* o2 = o1 + (size_t)B_ * K_;                  // obj_labels   B,K
    float* o3 = o2 + (size_t)B_ * K_;                  // sub_boxes    B,K,4
    float* o4 = o3 + (size_t)B_ * K_ * 4;              // obj_boxes    B,K,4
    float* o5 = o4 + (size_t)B_ * K_ * 4;              // keep         B,K

    // ---- init: hist, counters, suprow, keep_bits ----
    for (int i = tid; i < NB; i += NT) hist[i] = 0;
    if (tid < 400) ((u32*)(smem + OFF_SUPR))[tid] = 0;
    else if (tid < 404) keep_bits[tid - 400] = 0;
    if (tid == 0) { *s_cnt = 0; *sT = 0; }
    __syncthreads();

    // ---- Phase 1: coalesced 32-lane-group softmax, 2-ROW UNROLL (2x ILP on the
    // shfl/exp dependency chains) + p16 cache + histogram ----
    {
        int g = tid >> 5, l = tid & 31;
        bool have2 = (l < C_ - 64);   // l < 17
        int q = g;
        for (; q + 32 < Q_; q += 64) {
            const float* rowA = lg + q * C_;
            const float* rowB = lg + (q + 32) * C_;
            float a0 = rowA[l], a1 = rowA[l + 32];
            float b0 = rowB[l], b1 = rowB[l + 32];
            float a2 = have2 ? rowA[l + 64] : -INFINITY;
            float b2 = have2 ? rowB[l + 64] : -INFINITY;
            float ma = fmaxf(fmaxf(a0, a1), a2);
            float mb = fmaxf(fmaxf(b0, b1), b2);
            for (int off = 16; off; off >>= 1) {
                ma = fmaxf(ma, __shfl_xor(ma, off, 64));
                mb = fmaxf(mb, __shfl_xor(mb, off, 64));
            }
            float ea0 = __expf(a0 - ma), eb0 = __expf(b0 - mb);
            float ea1 = __expf(a1 - ma), eb1 = __expf(b1 - mb);
            float ea2 = have2 ? __expf(a2 - ma) : 0.f;
            float eb2 = have2 ? __expf(b2 - mb) : 0.f;
            float sa = ea0 + ea1 + ea2, sb = eb0 + eb1 + eb2;
            for (int off = 16; off; off >>= 1) {
                sa += __shfl_xor(sa, off, 64);
                sb += __shfl_xor(sb, off, 64);
            }
            float ria = 1.f / sa, rib = 1.f / sb;
            u32 A0 = __float_as_uint(ea0 * ria), A1 = __float_as_uint(ea1 * ria);
            u32 B0 = __float_as_uint(eb0 * rib), B1 = __float_as_uint(eb1 * rib);
            p16[q * C_ + l]             = (u16)(A0 >> 16);
            p16[q * C_ + l + 32]        = (u16)(A1 >> 16);
            p16[(q + 32) * C_ + l]      = (u16)(B0 >> 16);
            p16[(q + 32) * C_ + l + 32] = (u16)(B1 >> 16);
            atomicAdd(&hist[A0 >> 21], 1u);
            atomicAdd(&hist[A1 >> 21], 1u);
            atomicAdd(&hist[B0 >> 21], 1u);
            atomicAdd(&hist[B1 >> 21], 1u);
            if (have2) {
                u32 A2 = __float_as_uint(ea2 * ria), B2 = __float_as_uint(eb2 * rib);
                p16[q * C_ + l + 64]        = (u16)(A2 >> 16);
                p16[(q + 32) * C_ + l + 64] = (u16)(B2 >> 16);
                atomicAdd(&hist[A2 >> 21], 1u);
                atomicAdd(&hist[B2 >> 21], 1u);
            }
            if (l == 0) {
                rowmax[q] = ma; rinv[q] = ria;
                rowmax[q + 32] = mb; rinv[q + 32] = rib;
            }
        }
        if (q < Q_) {   // odd tail row
            const float* row = lg + q * C_;
            float v0 = row[l], v1 = row[l + 32];
            float v2 = have2 ? row[l + 64] : -INFINITY;
            float m = fmaxf(fmaxf(v0, v1), v2);
            for (int off = 16; off; off >>= 1) m = fmaxf(m, __shfl_xor(m, off, 64));
            float e0 = __expf(v0 - m), e1 = __expf(v1 - m);
            float e2 = have2 ? __expf(v2 - m) : 0.f;
            float s = e0 + e1 + e2;
            for (int off = 16; off; off >>= 1) s += __shfl_xor(s, off, 64);
            float ri = 1.f / s;
            u32 b0 = __float_as_uint(e0 * ri), b1 = __float_as_uint(e1 * ri);
            p16[q * C_ + l]      = (u16)(b0 >> 16);
            p16[q * C_ + l + 32] = (u16)(b1 >> 16);
            atomicAdd(&hist[b0 >> 21], 1u);
            atomicAdd(&hist[b1 >> 21], 1u);
            if (have2) {
                u32 b2 = __float_as_uint(e2 * ri);
                p16[q * C_ + l + 64] = (u16)(b2 >> 16);
                atomicAdd(&hist[b2 >> 21], 1u);
            }
            if (l == 0) { rowmax[q] = m; rinv[q] = ri; }
        }
    }
    __syncthreads();

    // ---- Phase 3: threshold bin T — wave-0 two-level suffix scan, one barrier ----
    if (tid < 64) {
        int d = tid;
        u32 c = 0;
        int base = d * 32;                     // 32 bins/lane
        for (int k = 0; k < 32; k++) c += hist[base + k];
        u32 suf = c;                           // suffix sum over lanes d..63
        #pragma unroll
        for (int off = 1; off < 64; off <<= 1) {
            u32 o = (u32)__shfl_down((int)suf, off, 64);
            suf += (d + off < 64) ? o : 0;
        }
        u32 above_chunk = suf - c;             // count in bins strictly above my chunk
        bool own = (above_chunk < (u32)K_) && (above_chunk + c >= (u32)K_);
        u64 mask = __ballot(own);
        int d0 = __ffsll((long long)mask) - 1; // exactly one lane owns
        u32 above0 = (u32)__shfl((int)above_chunk, d0, 64);
        // level 2: lanes 0..31 each take one bin of chunk d0
        u32 h = (d < 32) ? hist[d0 * 32 + d] : 0;
        u32 suf2 = h;
        #pragma unroll
        for (int off = 1; off < 64; off <<= 1) {
            u32 o = (u32)__shfl_down((int)suf2, off, 64);
            suf2 += (d + off < 64) ? o : 0;
        }
        u32 above_bin = above0 + (suf2 - h);
        if (d < 32 && above_bin < (u32)K_ && above_bin + h >= (u32)K_)
            *sT = d0 * 32 + d;
    }
    __syncthreads();   // sT published; wave-0 hist reads done -> cand may alias
    const int T = *sT;

    // ---- Phase 4: scan p16; exact keys recomputed only for candidates ----
    for (int i = tid; i < QC_; i += NT) {
        u32 pb = p16[i];
        if ((int)(pb >> 5) >= T) {
            u32 pos = atomicAdd(s_cnt, 1u);
            if (pos < (u32)CAP) {
                int q = i / C_;
                float p = __expf(lg[i] - rowmax[q]) * rinv[q];  // bit-identical to phase 1
                cand[pos] = ((u64)__float_as_uint(p) << 32) | (u32)(~i);
            }
        }
    }
    __syncthreads();
    const int ncand = (int)*s_cnt;

    auto cswap = [](u64& a, u64& bb, bool up) {
        if ((a > bb) == up) { u64 t = a; a = bb; bb = t; }
    };

    if (ncand <= 256) {
        // ---- Phase 5a: register-resident bitonic-256 on wave 0 — zero barriers ----
        if (tid < 64) {
            u64 v0 = (tid < ncand) ? cand[tid] : 0ull;
            u64 v1 = (64 + tid < ncand) ? cand[64 + tid] : 0ull;
            u64 v2 = (128 + tid < ncand) ? cand[128 + tid] : 0ull;
            u64 v3 = (192 + tid < ncand) ? cand[192 + tid] : 0ull;
            for (int k = 2; k <= 256; k <<= 1) {
                for (int j = k >> 1; j > 0; j >>= 1) {
                    if (j == 128) {
                        cswap(v0, v2, true);
                        cswap(v1, v3, true);
                    } else if (j == 64) {
                        cswap(v0, v1, true);
                        cswap(v2, v3, (k == 256));
                    } else {
                        auto step = [&](u64& v, int ebase) {
                            u64 pv = shfl_xor_u64(v, j);
                            int e = ebase + tid;
                            bool up = ((e & k) == 0);
                            bool lower = ((e & j) == 0);
                            u64 mn = v < pv ? v : pv;
                            u64 mx = v < pv ? pv : v;
                            v = (lower == up) ? mn : mx;
                        };
                        step(v0, 0); step(v1, 64); step(v2, 128); step(v3, 192);
                    }
                }
            }
            int e2 = 128 + tid;
            if (e2 >= 156) {
                int t = 255 - e2;
                sel_val[t] = __uint_as_float((u32)(v2 >> 32));
                sel_idx[t] = ~(u32)v2;
            }
            int t3 = 255 - (192 + tid);
            sel_val[t3] = __uint_as_float((u32)(v3 >> 32));
            sel_idx[t3] = ~(u32)v3;
        }
    } else if (ncand <= CAP) {
        // ---- Phase 5b: LDS bitonic-1024 fallback ----
        for (int e = tid; e < CAP; e += NT)
            if (e >= ncand) cand[e] = 0;
        __syncthreads();
        for (int k = 2; k <= CAP; k <<= 1) {
            for (int j = k >> 1; j > 0; j >>= 1) {
                int e = tid, partner = e ^ j;
                if (partner > e) {
                    u64 a = cand[e], bb = cand[partner];
                    bool up = ((e & k) == 0);
                    if ((a > bb) == up) { cand[e] = bb; cand[partner] = a; }
                }
                __syncthreads();
            }
        }
        if (tid < K_) {
            u64 m = cand[CAP - 1 - tid];
            sel_val[tid] = __uint_as_float((u32)(m >> 32));
            sel_idx[tid] = ~(u32)m;
        }
    } else {
        // ---- Phase 5c (near-dead): 100-round argmax with strict-less chaining ----
        if (tid == 0) *s_prev = ~0ull;
        __syncthreads();
        for (int r = 0; r < K_; r++) {
            u64 prev = *s_prev;
            u64 local = 0;
            for (int i = tid; i < QC_; i += NT) {
                int q = i / C_;
                float p = __expf(lg[i] - rowmax[q]) * rinv[q];
                u64 key = ((u64)__float_as_uint(p) << 32) | (u32)(~i);
                if (key < prev && key > local) local = key;
            }
            for (int off = 32; off > 0; off >>= 1) {
                u64 o = shfl_xor_u64(local, off);
                if (o > local) local = o;
            }
            if ((tid & 63) == 0) wred[tid >> 6] = local;
            __syncthreads();
            if (tid == 0) {
                u64 m = wred[0];
                for (int wv = 1; wv < 16; wv++) if (wred[wv] > m) m = wred[wv];
                *s_prev = m;
                u32 idx = ~(u32)m;
                if (idx >= (u32)QC_) idx = 0;
                sel_val[r] = __uint_as_float((u32)(m >> 32));
                sel_idx[r] = idx;
            }
            __syncthreads();
        }
    }
    __syncthreads();   // sel_* visible; p16/hist/cand/rowstats dead

    // ---- Phase 5.5+6 merged: box gather (tid<100) runs concurrently with
    // per-wave hoi-score rows (direct global write, in-wave max reduce) ----
    if (tid < K_) {
        int idx = (int)sel_idx[tid];
        int q = idx / C_;
        float iw = (float)tsizes[b * 2 + 1];
        float ih = (float)tsizes[b * 2 + 0];
        float4 sb = ((const float4*)sub_boxes_in)[(size_t)b * Q_ + q];
        float4 ob = ((const float4*)obj_boxes_in)[(size_t)b * Q_ + q];
        bsub[tid][0] = (sb.x - 0.5f * sb.z) * iw; bsub[tid][1] = (sb.y - 0.5f * sb.w) * ih;
        bsub[tid][2] = (sb.x + 0.5f * sb.z) * iw; bsub[tid][3] = (sb.y + 0.5f * sb.w) * ih;
        bobj[tid][0] = (ob.x - 0.5f * ob.z) * iw; bobj[tid][1] = (ob.y - 0.5f * ob.w) * ih;
        bobj[tid][2] = (ob.x + 0.5f * ob.z) * iw; bobj[tid][3] = (ob.y + 0.5f * ob.w) * ih;
    }
    {
        int w = tid >> 6, l = tid & 63;
        for (int r = w; r < K_; r += 16) {
            int idx = (int)sel_idx[r];
            int q = idx / C_, lab = idx - q * C_;
            float val = sel_val[r];
            const float* vrow = verb_logits + ((size_t)b * Q_ + q) * V_;
            float* orow = o0 + (size_t)b * KV_ + r * V_;
            float x0 = vrow[l];
            float h0 = (1.f / (1.f + __expf(-x0))) * val * cm[l * C_ + lab];
            orow[l] = h0;
            float h1 = 0.f;
            if (l < V_ - 64) {
                float x1 = vrow[l + 64];
                h1 = (1.f / (1.f + __expf(-x1))) * val * cm[(l + 64) * C_ + lab];
                orow[l + 64] = h1;
            }
            float m = fmaxf(h0, h1);
            for (int off = 32; off; off >>= 1) m = fmaxf(m, __shfl_xor(m, off, 64));
            if (l == 0) maxbits[r] = __float_as_uint(m);
        }
    }
    __syncthreads();

    // ---- Phase 7: stable descending rank, 8 lanes/row ----
    if (tid < 800) {
        int r = tid >> 3, j = tid & 7;
        u64 kr = ((u64)maxbits[r] << 32) | (u32)(~r);
        int rank = 0;
        for (int k = 0; k < 13; k++) {
            int jj = j * 13 + k;
            if (jj < K_) {
                u64 kj = ((u64)maxbits[jj] << 32) | (u32)(~jj);
                rank += (kj > kr) ? 1 : 0;
            }
        }
        for (int off = 4; off; off >>= 1) rank += __shfl_xor(rank, off, 64);
        if (j == 0) order8[rank] = (u8)r;
    }
    __syncthreads();

    // ---- Phase 8a: 100x100 suppression bitmatrix in sorted space ----
    for (int e = tid; e < K_ * K_; e += NT) {
        int i = e / K_, j = e - i * K_;
        if (j > i) {
            int ri = order8[i], rj = order8[j];
            u32 li = sel_idx[ri] % (u32)C_, lj = sel_idx[rj] % (u32)C_;
            if (li == lj) {
                float o = iou1(bsub[ri], bsub[rj]) * iou1(bobj[ri], bobj[rj]);
                if (o > 0.5f)
                    atomicOr(&suprow[i][j >> 5], 1u << (j & 31));
            }
        }
    }
    __syncthreads();

    // ---- Phase 8b: greedy scan — single wave, register-resident ----
    if (tid < 64) {
        u32 ra0 = suprow[tid][0], ra1 = suprow[tid][1], ra2 = suprow[tid][2], ra3 = suprow[tid][3];
        u32 rb0 = 0, rb1 = 0, rb2 = 0, rb3 = 0;
        if (tid < K_ - 64) {
            rb0 = suprow[tid + 64][0]; rb1 = suprow[tid + 64][1];
            rb2 = suprow[tid + 64][2]; rb3 = suprow[tid + 64][3];
        }
        u32 acc[4] = {0, 0, 0, 0};
        u32 km[4]  = {0, 0, 0, 0};
        #pragma unroll
        for (int i = 0; i < K_; i++) {
            u32 r0, r1, r2, r3;
            if (i < 64) {
                r0 = (u32)__shfl((int)ra0, i, 64); r1 = (u32)__shfl((int)ra1, i, 64);
                r2 = (u32)__shfl((int)ra2, i, 64); r3 = (u32)__shfl((int)ra3, i, 64);
            } else {
                r0 = (u32)__shfl((int)rb0, i - 64, 64); r1 = (u32)__shfl((int)rb1, i - 64, 64);
                r2 = (u32)__shfl((int)rb2, i - 64, 64); r3 = (u32)__shfl((int)rb3, i - 64, 64);
            }
            bool sup_i = (acc[i >> 5] >> (i & 31)) & 1u;
            if (!sup_i) {
                km[i >> 5] |= 1u << (i & 31);
                acc[0] |= r0; acc[1] |= r1; acc[2] |= r2; acc[3] |= r3;
            }
        }
        if (tid == 0) { skeep[0] = km[0]; skeep[1] = km[1]; skeep[2] = km[2]; skeep[3] = km[3]; }
    }
    __syncthreads();
    if (tid < K_) {
        if ((skeep[tid >> 5] >> (tid & 31)) & 1u) {
            int r = order8[tid];
            atomicOr(&keep_bits[r >> 5], 1u << (r & 31));
        }
    }
    __syncthreads();

    // ---- Phase 9: zero suppressed rows of o0; small outputs ----
    {
        int w = tid >> 6, l = tid & 63;
        for (int r = w; r < K_; r += 16) {
            if (!((keep_bits[r >> 5] >> (r & 31)) & 1u)) {
                float* orow = o0 + (size_t)b * KV_ + r * V_;
                orow[l] = 0.f;
                if (l < V_ - 64) orow[l + 64] = 0.f;
            }
        }
    }
    if (tid < K_) {
        bool kp = (keep_bits[tid >> 5] >> (tid & 31)) & 1u;
        o1[(size_t)b * K_ + tid] = sel_val[tid];
        o2[(size_t)b * K_ + tid] = (float)(sel_idx[tid] % (u32)C_);
        o5[(size_t)b * K_ + tid] = kp ? 1.f : 0.f;
    }
    if (tid < K_ * 4) {
        int r = tid >> 2, k = tid & 3;
        o3[((size_t)b * K_) * 4 + tid] = bsub[r][k];
        o4[((size_t)b * K_) * 4 + tid] = bobj[r][k];
    }
}

extern "C" void kernel_launch(void* const* d_in, const int* in_sizes, int n_in,
                              void* d_out, int out_size, void* d_ws, size_t ws_size,
                              hipStream_t stream) {
    const float* obj_logits  = (const float*)d_in[0];
    const float* verb_logits = (const float*)d_in[1];
    const float* sub_boxes   = (const float*)d_in[2];
    const float* obj_boxes   = (const float*)d_in[3];
    const float* cm          = (const float*)d_in[4];
    const int*   ts          = (const int*)d_in[5];
    hipLaunchKernelGGL(hoi_kernel, dim3(B_), dim3(NT), 0, stream,
                       obj_logits, verb_logits, sub_boxes, obj_boxes, cm, ts,
                       (float*)d_out);
}